// Round 4
// baseline (8377.529 us; speedup 1.0000x reference)
//
#include <hip/hip_runtime.h>

#define NB 4
#define NT 32
#define ND 768
#define NK 1024
#define NN 256
#define NINIT 4
#define NFRAMES 28
#define NM 1280

typedef _Float16 f16;
typedef f16 f16x8 __attribute__((ext_vector_type(8)));
typedef f16 f16x4 __attribute__((ext_vector_type(4)));
typedef float f32x4 __attribute__((ext_vector_type(4)));

#define GLOAD_LDS(g, s) __builtin_amdgcn_global_load_lds( \
    (const __attribute__((address_space(1))) void*)(g),   \
    (__attribute__((address_space(3))) void*)(s), 16, 0, 0)

// row-dependent XOR swizzle, closed within a 64-byte row (bits 4-5 only).
__device__ __forceinline__ int swz(int r) { return ((r >> 1) & 3) << 4; }

// ---------------- init: mem copy, counts=1, f16 split, cnorm, packed reset ----
__global__ __launch_bounds__(256) void k_init(
    const float* __restrict__ V, float* __restrict__ mem, float* __restrict__ cnt,
    f16* __restrict__ dH, f16* __restrict__ dL,
    float* __restrict__ cnorm, unsigned long long* __restrict__ packed0)
{
    int row = blockIdx.x * 4 + (threadIdx.x >> 6);   // 0..4095
    int lane = threadIdx.x & 63;
    int b = row >> 10, k = row & 1023;
    const float4* src = (const float4*)(V + ((size_t)b * NT * NN + k) * ND);
    float4* mrow = (float4*)(mem + (size_t)row * ND);
    f16x4* hrow = (f16x4*)(dH + ((size_t)b * NM + k) * ND);
    f16x4* lrow = (f16x4*)(dL + ((size_t)b * NM + k) * ND);
    float s2 = 0.f;
#pragma unroll
    for (int jj = 0; jj < 3; ++jj) {
        float4 x = src[lane + 64 * jj];
        mrow[lane + 64 * jj] = x;
        f16x4 h, lo;
        h[0] = (f16)x.x; lo[0] = (f16)(x.x - (float)h[0]);
        h[1] = (f16)x.y; lo[1] = (f16)(x.y - (float)h[1]);
        h[2] = (f16)x.z; lo[2] = (f16)(x.z - (float)h[2]);
        h[3] = (f16)x.w; lo[3] = (f16)(x.w - (float)h[3]);
        hrow[lane + 64 * jj] = h;
        lrow[lane + 64 * jj] = lo;
        s2 += x.x * x.x + x.y * x.y + x.z * x.z + x.w * x.w;
    }
#pragma unroll
    for (int off = 32; off; off >>= 1) s2 += __shfl_xor(s2, off);
    if (lane == 0) { cnorm[row] = s2; cnt[row] = 1.0f; packed0[(size_t)b * NM + k] = ~0ull; }
    if (lane == 1 && k < NN) packed0[(size_t)b * NM + NK + k] = ~0ull;
}

// ---------------- per-frame: split the 256 new tokens ----------------
__global__ __launch_bounds__(256) void k_prep(const float* __restrict__ V, int t,
                                              f16* __restrict__ dH, f16* __restrict__ dL) {
    int row = blockIdx.x * 4 + (threadIdx.x >> 6);  // 0..1023
    int lane = threadIdx.x & 63;
    int b = row >> 8, n = row & 255;
    const float4* src = (const float4*)(V + (((size_t)b * NT + t) * NN + n) * ND);
    f16x4* hrow = (f16x4*)(dH + ((size_t)b * NM + NK + n) * ND);
    f16x4* lrow = (f16x4*)(dL + ((size_t)b * NM + NK + n) * ND);
#pragma unroll
    for (int jj = 0; jj < 3; ++jj) {
        float4 x = src[lane + 64 * jj];
        f16x4 h, lo;
        h[0] = (f16)x.x; lo[0] = (f16)(x.x - (float)h[0]);
        h[1] = (f16)x.y; lo[1] = (f16)(x.y - (float)h[1]);
        h[2] = (f16)x.z; lo[2] = (f16)(x.z - (float)h[2]);
        h[3] = (f16)x.w; lo[3] = (f16)(x.w - (float)h[3]);
        hrow[lane + 64 * jj] = h;
        lrow[lane + 64 * jj] = lo;
    }
}

// ---------------- MFMA score + argmin (packed atomicMin) ----------------
__global__ __launch_bounds__(128) void k_score(
    const f16* __restrict__ AH, const f16* __restrict__ AL,   // (B, NM, ND)
    const f16* __restrict__ BH, const f16* __restrict__ BL,   // (B, bRows, ND)
    int bRows,
    const float* __restrict__ cnorm,                          // (B, NK)
    unsigned long long* __restrict__ packed)                  // (B, NM)
{
    __shared__ float4 ldsbuf[1536];   // 24 KB: AH 8K | AL 8K | BH 4K | BL 4K
    char* lds = (char*)ldsbuf;
    int bid = blockIdx.x;
    int sz = (bid & 7) * 80 + (bid >> 3);      // XCD-aware (640 % 8 == 0)
    int b = sz / 160;
    int rem = sz - b * 160;
    int mt = rem >> 4, kt = rem & 15;
    int tid = threadIdx.x;
    int w = tid >> 6, l = tid & 63;

    const char* sp[12];
#pragma unroll
    for (int i = 0; i < 12; ++i) {
        int j = w * 12 + i;
        const f16* base; int r, grow;
        if (j < 8)       { r = 16 * j + (l >> 2);        grow = b * NM + mt * 128 + r;    base = AH; }
        else if (j < 16) { r = 16 * (j - 8) + (l >> 2);  grow = b * NM + mt * 128 + r;    base = AL; }
        else if (j < 20) { r = 16 * (j - 16) + (l >> 2); grow = b * bRows + kt * 64 + r;  base = BH; }
        else             { r = 16 * (j - 20) + (l >> 2); grow = b * bRows + kt * 64 + r;  base = BL; }
        int colB = ((l & 3) * 16) ^ swz(r);              // inverse of read-side swizzle
        sp[i] = (const char*)(base + (size_t)grow * ND) + colB;
    }

    int aoff[4], boff[4];
#pragma unroll
    for (int mi = 0; mi < 4; ++mi) {
        int r = w * 64 + mi * 16 + (l & 15);
        aoff[mi] = r * 64 + (((l >> 4) * 16) ^ swz(r));
    }
#pragma unroll
    for (int nj = 0; nj < 4; ++nj) {
        int r = nj * 16 + (l & 15);
        boff[nj] = r * 64 + (((l >> 4) * 16) ^ swz(r));
    }

    f32x4 acc[4][4] = {};

    for (int c = 0; c < 24; ++c) {
#pragma unroll
        for (int i = 0; i < 12; ++i) {
            GLOAD_LDS(sp[i], lds + (w * 12 + i) * 1024);
            sp[i] += 64;
        }
        __syncthreads();
        f16x8 ah[4], al[4], bh[4], bl[4];
#pragma unroll
        for (int mi = 0; mi < 4; ++mi) {
            ah[mi] = *(const f16x8*)(lds + aoff[mi]);
            al[mi] = *(const f16x8*)(lds + 8192 + aoff[mi]);
        }
#pragma unroll
        for (int nj = 0; nj < 4; ++nj) {
            bh[nj] = *(const f16x8*)(lds + 16384 + boff[nj]);
            bl[nj] = *(const f16x8*)(lds + 20480 + boff[nj]);
        }
#pragma unroll
        for (int mi = 0; mi < 4; ++mi)
#pragma unroll
            for (int nj = 0; nj < 4; ++nj) {
                acc[mi][nj] = __builtin_amdgcn_mfma_f32_16x16x32_f16(ah[mi], bh[nj], acc[mi][nj], 0, 0, 0);
                acc[mi][nj] = __builtin_amdgcn_mfma_f32_16x16x32_f16(ah[mi], bl[nj], acc[mi][nj], 0, 0, 0);
                acc[mi][nj] = __builtin_amdgcn_mfma_f32_16x16x32_f16(al[mi], bh[nj], acc[mi][nj], 0, 0, 0);
            }
        __syncthreads();
    }

    int colb = kt * 64 + (l & 15);
    float cn[4];
#pragma unroll
    for (int nj = 0; nj < 4; ++nj) cn[nj] = cnorm[b * NK + colb + nj * 16];
    size_t prow = (size_t)b * NM + mt * 128 + w * 64 + (l >> 4) * 4;
#pragma unroll
    for (int mi = 0; mi < 4; ++mi) {
#pragma unroll
        for (int rg = 0; rg < 4; ++rg) {
            float bv = 1e30f; int bi = 0;
#pragma unroll
            for (int nj = 0; nj < 4; ++nj) {
                float s = cn[nj] - 2.0f * acc[mi][nj][rg];
                int ki = colb + nj * 16;
                if (s < bv) { bv = s; bi = ki; }
            }
#pragma unroll
            for (int off = 1; off < 16; off <<= 1) {
                float ov = __shfl_xor(bv, off);
                int   oi = __shfl_xor(bi, off);
                if (ov < bv || (ov == bv && oi < bi)) { bv = ov; bi = oi; }
            }
            if ((l & 15) == 0) {
                unsigned u = __float_as_uint(bv);
                unsigned key = (u >> 31) ? ~u : (u | 0x80000000u);
                atomicMin(&packed[prow + mi * 16 + rg],
                          ((unsigned long long)key << 32) | (unsigned)bi);
            }
        }
    }
}

// ---------------- build compact member lists (CSR) + reset other packed ----
__global__ __launch_bounds__(1024) void k_lists(
    const unsigned long long* __restrict__ packed,   // (B,NM) just written
    unsigned long long* __restrict__ packedOther,    // reset to ~0 for next score
    int* __restrict__ lstCnt, int* __restrict__ lstBase,  // (B,NK)
    int* __restrict__ lstIdx)                             // (B,NM)
{
    __shared__ int cntL[NK];
    __shared__ int scanA[NK];
    __shared__ int cursor[NK];
    __shared__ int aSh[NM];
    int b = blockIdx.x, tid = threadIdx.x;
    cntL[tid] = 0;
    __syncthreads();
    for (int m = tid; m < NM; m += 1024) {
        int a = (int)(unsigned)(packed[(size_t)b * NM + m] & 0xffffffffull);
        aSh[m] = a;
        atomicAdd(&cntL[a], 1);
        packedOther[(size_t)b * NM + m] = ~0ull;
    }
    __syncthreads();
    int v = cntL[tid];
    scanA[tid] = v;
    __syncthreads();
#pragma unroll
    for (int off = 1; off < 1024; off <<= 1) {
        int add = (tid >= off) ? scanA[tid - off] : 0;
        __syncthreads();
        scanA[tid] += add;
        __syncthreads();
    }
    int base = scanA[tid] - v;   // exclusive
    cursor[tid] = base;
    lstCnt[b * NK + tid] = v;
    lstBase[b * NK + tid] = base;
    __syncthreads();
    for (int m = tid; m < NM; m += 1024) {
        int pos = atomicAdd(&cursor[aSh[m]], 1);
        lstIdx[(size_t)b * NM + pos] = m;
    }
}

// ---------------- center update + fused split/cnorm ----------
__global__ __launch_bounds__(256) void k_update(
    const float* __restrict__ Cen, const float* __restrict__ memFS,
    const float* __restrict__ V, int t,
    const float* __restrict__ cntFS,
    const int* __restrict__ lstCnt, const int* __restrict__ lstBase,
    const int* __restrict__ lstIdx,
    float* __restrict__ Cout, float* __restrict__ cntOut,
    f16* __restrict__ outH, f16* __restrict__ outL, int outStride,
    float* __restrict__ cnormOut)
{
    int row = blockIdx.x * 4 + (threadIdx.x >> 6);   // b*NK + k
    int lane = threadIdx.x & 63;
    int b = row >> 10, k = row & 1023;
    int n = lstCnt[row], base = lstBase[row];
    const int* lst = lstIdx + (size_t)b * NM + base;
    float ax[3] = {}, ay[3] = {}, az[3] = {}, aw[3] = {};
    float sumw = 0.f;
    for (int i = 0; i < n; ++i) {
        int mm = lst[i];
        float wgt = (mm < NK) ? cntFS[b * NK + mm] : 1.0f;
        const float4* drow = (mm < NK)
            ? (const float4*)(memFS + ((size_t)b * NK + mm) * ND)
            : (const float4*)(V + (((size_t)b * NT + t) * NN + (mm - NK)) * (size_t)ND);
        sumw += wgt;
#pragma unroll
        for (int jj = 0; jj < 3; ++jj) {
            float4 x = drow[lane + 64 * jj];
            ax[jj] += wgt * x.x; ay[jj] += wgt * x.y;
            az[jj] += wgt * x.z; aw[jj] += wgt * x.w;
        }
    }
    float inv = 1.0f / (sumw + 1e-8f);
    bool empty = sumw < 1e-6f;
    const float4* crow = (const float4*)(Cen + (size_t)row * ND);
    float4* orow = (float4*)(Cout + (size_t)row * ND);
    f16x4* hrow = (f16x4*)(outH + ((size_t)b * outStride + k) * ND);
    f16x4* lrow = (f16x4*)(outL + ((size_t)b * outStride + k) * ND);
    float s2 = 0.f;
#pragma unroll
    for (int jj = 0; jj < 3; ++jj) {
        float4 vv;
        if (empty) vv = crow[lane + 64 * jj];
        else { vv.x = ax[jj] * inv; vv.y = ay[jj] * inv; vv.z = az[jj] * inv; vv.w = aw[jj] * inv; }
        orow[lane + 64 * jj] = vv;
        f16x4 h, lo;
        h[0] = (f16)vv.x; lo[0] = (f16)(vv.x - (float)h[0]);
        h[1] = (f16)vv.y; lo[1] = (f16)(vv.y - (float)h[1]);
        h[2] = (f16)vv.z; lo[2] = (f16)(vv.z - (float)h[2]);
        h[3] = (f16)vv.w; lo[3] = (f16)(vv.w - (float)h[3]);
        hrow[lane + 64 * jj] = h;
        lrow[lane + 64 * jj] = lo;
        s2 += vv.x * vv.x + vv.y * vv.y + vv.z * vv.z + vv.w * vv.w;
    }
#pragma unroll
    for (int off = 32; off; off >>= 1) s2 += __shfl_xor(s2, off);
    if (lane == 0) { cnormOut[row] = s2; cntOut[row] = sumw; }
}

// ---------------- host ----------------
extern "C" void kernel_launch(void* const* d_in, const int* in_sizes, int n_in,
                              void* d_out, int out_size, void* d_ws, size_t ws_size,
                              hipStream_t stream) {
    const float* V = (const float*)d_in[0];
    float* out = (float*)d_out;
    char* p = (char*)d_ws;
    auto take = [&](size_t bytes) { char* r = p; p += (bytes + 255) & ~(size_t)255; return r; };
    const size_t memB = (size_t)NB * NK * ND * 4;
    float* mem0 = (float*)take(memB);
    float* mem1 = (float*)take(memB);
    float* cnt0 = (float*)take(NB * NK * 4);
    float* cnt1 = (float*)take(NB * NK * 4);
    float* cntS = (float*)take(NB * NK * 4);
    float* cnor = (float*)take(NB * NK * 4);
    unsigned long long* packed0 = (unsigned long long*)take(NB * NM * 8);
    unsigned long long* packed1 = (unsigned long long*)take(NB * NM * 8);
    int* lstCnt  = (int*)take(NB * NK * 4);
    int* lstBase = (int*)take(NB * NK * 4);
    int* lstIdx  = (int*)take(NB * NM * 4);
    f16* dataH = (f16*)take((size_t)NB * NM * ND * 2);
    f16* dataL = (f16*)take((size_t)NB * NM * ND * 2);
    f16* cenH  = (f16*)take((size_t)NB * NK * ND * 2);
    f16* cenL  = (f16*)take((size_t)NB * NK * ND * 2);

    k_init<<<1024, 256, 0, stream>>>(V, mem0, cnt0, dataH, dataL, cnor, packed0);

    float* mem[2] = {mem0, mem1};
    float* cnt[2] = {cnt0, cnt1};

    for (int f = 0; f < NFRAMES; ++f) {
        int s = f & 1, t = NINIT + f;
        float* mFS = mem[s];
        float* cFS = cnt[s];

        k_prep<<<256, 256, 0, stream>>>(V, t, dataH, dataL);

        // iter 1: centers = memory rows (split lives in dataH/L rows 0..1023)
        k_score<<<640, 128, 0, stream>>>(dataH, dataL, dataH, dataL, NM, cnor, packed0);
        k_lists<<<NB, 1024, 0, stream>>>(packed0, packed1, lstCnt, lstBase, lstIdx);
        k_update<<<1024, 256, 0, stream>>>(mFS, mFS, V, t, cFS, lstCnt, lstBase, lstIdx,
                                           out, cntS, cenH, cenL, NK, cnor);

        // iter 2: centers = tmp centers in d_out (split in cenH/L)
        k_score<<<640, 128, 0, stream>>>(dataH, dataL, cenH, cenL, NK, cnor, packed1);
        k_lists<<<NB, 1024, 0, stream>>>(packed1, packed0, lstCnt, lstBase, lstIdx);
        float* dst = (f == NFRAMES - 1) ? out : mem[1 - s];
        k_update<<<1024, 256, 0, stream>>>(out, mFS, V, t, cFS, lstCnt, lstBase, lstIdx,
                                           dst, cnt[1 - s], dataH, dataL, NM, cnor);
    }
}

// Round 5
// 5463.979 us; speedup vs baseline: 1.5332x; 1.5332x over previous
//
#include <hip/hip_runtime.h>

#define NB 4
#define NT 32
#define ND 768
#define NK 1024
#define NN 256
#define NINIT 4
#define NFRAMES 28
#define NM 1280

typedef _Float16 f16;
typedef f16 f16x8 __attribute__((ext_vector_type(8)));
typedef f16 f16x4 __attribute__((ext_vector_type(4)));
typedef float f32x4 __attribute__((ext_vector_type(4)));

#define GLOAD_LDS(g, s) __builtin_amdgcn_global_load_lds( \
    (const __attribute__((address_space(1))) void*)(g),   \
    (__attribute__((address_space(3))) void*)(s), 16, 0, 0)

// row-dependent XOR swizzle, closed within a 64-byte row (bits 4-5 only).
__device__ __forceinline__ int swz(int r) { return ((r >> 1) & 3) << 4; }

// ---------------- init: mem copy, counts=1, f16 split, cnorm partials, reset --
__global__ __launch_bounds__(256) void k_init(
    const float* __restrict__ V, float* __restrict__ mem, float* __restrict__ cnt,
    f16* __restrict__ dH, f16* __restrict__ dL,
    float* __restrict__ cnP, unsigned long long* __restrict__ packed0)
{
    int row = blockIdx.x * 4 + (threadIdx.x >> 6);   // 0..4095
    int lane = threadIdx.x & 63;
    int b = row >> 10, k = row & 1023;
    const float4* src = (const float4*)(V + ((size_t)b * NT * NN + k) * ND);
    float4* mrow = (float4*)(mem + (size_t)row * ND);
    f16x4* hrow = (f16x4*)(dH + ((size_t)b * NM + k) * ND);
    f16x4* lrow = (f16x4*)(dL + ((size_t)b * NM + k) * ND);
    float s2 = 0.f;
#pragma unroll
    for (int jj = 0; jj < 3; ++jj) {
        float4 x = src[lane + 64 * jj];
        mrow[lane + 64 * jj] = x;
        f16x4 h, lo;
        h[0] = (f16)x.x; lo[0] = (f16)(x.x - (float)h[0]);
        h[1] = (f16)x.y; lo[1] = (f16)(x.y - (float)h[1]);
        h[2] = (f16)x.z; lo[2] = (f16)(x.z - (float)h[2]);
        h[3] = (f16)x.w; lo[3] = (f16)(x.w - (float)h[3]);
        hrow[lane + 64 * jj] = h;
        lrow[lane + 64 * jj] = lo;
        s2 += x.x * x.x + x.y * x.y + x.z * x.z + x.w * x.w;
    }
#pragma unroll
    for (int off = 32; off; off >>= 1) s2 += __shfl_xor(s2, off);
    if (lane == 0) {
        cnP[row * 3] = s2; cnP[row * 3 + 1] = 0.f; cnP[row * 3 + 2] = 0.f;
        cnt[row] = 1.0f; packed0[(size_t)b * NM + k] = ~0ull;
    }
    if (lane == 1 && k < NN) packed0[(size_t)b * NM + NK + k] = ~0ull;
}

// ---------------- per-frame: split the 256 new tokens ----------------
__global__ __launch_bounds__(256) void k_prep(const float* __restrict__ V, int t,
                                              f16* __restrict__ dH, f16* __restrict__ dL) {
    int row = blockIdx.x * 4 + (threadIdx.x >> 6);  // 0..1023
    int lane = threadIdx.x & 63;
    int b = row >> 8, n = row & 255;
    const float4* src = (const float4*)(V + (((size_t)b * NT + t) * NN + n) * ND);
    f16x4* hrow = (f16x4*)(dH + ((size_t)b * NM + NK + n) * ND);
    f16x4* lrow = (f16x4*)(dL + ((size_t)b * NM + NK + n) * ND);
#pragma unroll
    for (int jj = 0; jj < 3; ++jj) {
        float4 x = src[lane + 64 * jj];
        f16x4 h, lo;
        h[0] = (f16)x.x; lo[0] = (f16)(x.x - (float)h[0]);
        h[1] = (f16)x.y; lo[1] = (f16)(x.y - (float)h[1]);
        h[2] = (f16)x.z; lo[2] = (f16)(x.z - (float)h[2]);
        h[3] = (f16)x.w; lo[3] = (f16)(x.w - (float)h[3]);
        hrow[lane + 64 * jj] = h;
        lrow[lane + 64 * jj] = lo;
    }
}

// ---------------- MFMA score + argmin (packed atomicMin) ----------------
// grid = NB*mTiles*16 blocks x 128 threads. Tile 128(M) x 64(K centers).
__global__ __launch_bounds__(128) void k_score(
    const f16* __restrict__ AH, const f16* __restrict__ AL,   // (B, NM, ND)
    const f16* __restrict__ BH, const f16* __restrict__ BL,   // (B, bRows, ND)
    int bRows, int mOff, int mTiles,
    const float* __restrict__ cnP,                            // (B*NK, 3) partials
    unsigned long long* __restrict__ packed)                  // (B, NM)
{
    __shared__ float4 ldsbuf[1536];   // 24 KB: AH 8K | AL 8K | BH 4K | BL 4K
    char* lds = (char*)ldsbuf;
    int bid = blockIdx.x;
    int cpx = (int)gridDim.x >> 3;
    int sz = (bid & 7) * cpx + (bid >> 3);     // XCD-aware (grid % 8 == 0)
    int pb = mTiles * 16;
    int b = sz / pb;
    int rem = sz - b * pb;
    int mt = rem >> 4, kt = rem & 15;
    int tid = threadIdx.x;
    int w = tid >> 6, l = tid & 63;

    const char* sp[12];
#pragma unroll
    for (int i = 0; i < 12; ++i) {
        int j = w * 12 + i;
        const f16* base; int r, grow;
        if (j < 8)       { r = 16 * j + (l >> 2);        grow = b * NM + mOff + mt * 128 + r; base = AH; }
        else if (j < 16) { r = 16 * (j - 8) + (l >> 2);  grow = b * NM + mOff + mt * 128 + r; base = AL; }
        else if (j < 20) { r = 16 * (j - 16) + (l >> 2); grow = b * bRows + kt * 64 + r;      base = BH; }
        else             { r = 16 * (j - 20) + (l >> 2); grow = b * bRows + kt * 64 + r;      base = BL; }
        int colB = ((l & 3) * 16) ^ swz(r);              // inverse of read-side swizzle
        sp[i] = (const char*)(base + (size_t)grow * ND) + colB;
    }

    int aoff[4], boff[4];
#pragma unroll
    for (int mi = 0; mi < 4; ++mi) {
        int r = w * 64 + mi * 16 + (l & 15);
        aoff[mi] = r * 64 + (((l >> 4) * 16) ^ swz(r));
    }
#pragma unroll
    for (int nj = 0; nj < 4; ++nj) {
        int r = nj * 16 + (l & 15);
        boff[nj] = r * 64 + (((l >> 4) * 16) ^ swz(r));
    }

    f32x4 acc[4][4] = {};

    for (int c = 0; c < 24; ++c) {
#pragma unroll
        for (int i = 0; i < 12; ++i) {
            GLOAD_LDS(sp[i], lds + (w * 12 + i) * 1024);
            sp[i] += 64;
        }
        __syncthreads();
        f16x8 ah[4], al[4], bh[4], bl[4];
#pragma unroll
        for (int mi = 0; mi < 4; ++mi) {
            ah[mi] = *(const f16x8*)(lds + aoff[mi]);
            al[mi] = *(const f16x8*)(lds + 8192 + aoff[mi]);
        }
#pragma unroll
        for (int nj = 0; nj < 4; ++nj) {
            bh[nj] = *(const f16x8*)(lds + 16384 + boff[nj]);
            bl[nj] = *(const f16x8*)(lds + 20480 + boff[nj]);
        }
#pragma unroll
        for (int mi = 0; mi < 4; ++mi)
#pragma unroll
            for (int nj = 0; nj < 4; ++nj) {
                acc[mi][nj] = __builtin_amdgcn_mfma_f32_16x16x32_f16(ah[mi], bh[nj], acc[mi][nj], 0, 0, 0);
                acc[mi][nj] = __builtin_amdgcn_mfma_f32_16x16x32_f16(ah[mi], bl[nj], acc[mi][nj], 0, 0, 0);
                acc[mi][nj] = __builtin_amdgcn_mfma_f32_16x16x32_f16(al[mi], bh[nj], acc[mi][nj], 0, 0, 0);
            }
        __syncthreads();
    }

    int colb = kt * 64 + (l & 15);
    float cn[4];
#pragma unroll
    for (int nj = 0; nj < 4; ++nj) {
        int kc = b * NK + colb + nj * 16;
        cn[nj] = cnP[kc * 3] + cnP[kc * 3 + 1] + cnP[kc * 3 + 2];
    }
    size_t prow = (size_t)b * NM + mOff + mt * 128 + w * 64 + (l >> 4) * 4;
#pragma unroll
    for (int mi = 0; mi < 4; ++mi) {
#pragma unroll
        for (int rg = 0; rg < 4; ++rg) {
            float bv = 1e30f; int bi = 0;
#pragma unroll
            for (int nj = 0; nj < 4; ++nj) {
                float s = cn[nj] - 2.0f * acc[mi][nj][rg];
                int ki = colb + nj * 16;
                if (s < bv) { bv = s; bi = ki; }
            }
#pragma unroll
            for (int off = 1; off < 16; off <<= 1) {
                float ov = __shfl_xor(bv, off);
                int   oi = __shfl_xor(bi, off);
                if (ov < bv || (ov == bv && oi < bi)) { bv = ov; bi = oi; }
            }
            if ((l & 15) == 0) {
                unsigned u = __float_as_uint(bv);
                unsigned key = (u >> 31) ? ~u : (u | 0x80000000u);
                atomicMin(&packed[prow + mi * 16 + rg],
                          ((unsigned long long)key << 32) | (unsigned)bi);
            }
        }
    }
}

// ---------------- build compact member lists (CSR) + reset other packed ----
__global__ __launch_bounds__(1024) void k_lists(
    const unsigned long long* __restrict__ packed, int selfSeed,
    unsigned long long* __restrict__ packedOther,
    int2* __restrict__ cb, int* __restrict__ lstIdx)
{
    __shared__ int cntL[NK];
    __shared__ int scanA[NK];
    __shared__ int cursor[NK];
    __shared__ int aSh[NM];
    int b = blockIdx.x, tid = threadIdx.x;
    cntL[tid] = 0;
    __syncthreads();
    for (int m = tid; m < NM; m += 1024) {
        int a;
        if (selfSeed && m < NK) a = m;   // iter1: data row m IS center m
        else a = (int)(unsigned)(packed[(size_t)b * NM + m] & 0xffffffffull);
        aSh[m] = a;
        atomicAdd(&cntL[a], 1);
        packedOther[(size_t)b * NM + m] = ~0ull;
    }
    __syncthreads();
    int v = cntL[tid];
    scanA[tid] = v;
    __syncthreads();
#pragma unroll
    for (int off = 1; off < 1024; off <<= 1) {
        int add = (tid >= off) ? scanA[tid - off] : 0;
        __syncthreads();
        scanA[tid] += add;
        __syncthreads();
    }
    int base = scanA[tid] - v;   // exclusive
    cursor[tid] = base;
    cb[b * NK + tid] = make_int2(v, base);
    __syncthreads();
    for (int m = tid; m < NM; m += 1024) {
        int pos = atomicAdd(&cursor[aSh[m]], 1);
        lstIdx[(size_t)b * NM + pos] = m;
    }
}

// ---------------- center update: one wave per (row, 256-dim chunk) ----------
__global__ __launch_bounds__(256) void k_update(
    const float* __restrict__ Cen, const float* __restrict__ memFS,
    const float* __restrict__ V, int t,
    const float* __restrict__ cntFS,
    const int2* __restrict__ cb, const int* __restrict__ lstIdx,
    float* __restrict__ Cout, float* __restrict__ cntOut,
    f16* __restrict__ outH, f16* __restrict__ outL, int outStride,
    float* __restrict__ cnP)
{
    int g = blockIdx.x * 4 + (threadIdx.x >> 6);   // 0..12287
    int lane = threadIdx.x & 63;
    int row = g / 3, c = g - row * 3;              // row = b*NK+k, chunk c
    int b = row >> 10, k = row & 1023;
    int2 cnb = cb[row];
    int n = cnb.x, base = cnb.y;
    const int* lst = lstIdx + (size_t)b * NM + base;
    float sumw = 0.f;
    float4 acc = {0.f, 0.f, 0.f, 0.f};
    for (int i0 = 0; i0 < n; i0 += 4) {
        int idx[4]; float wg[4];
#pragma unroll
        for (int i = 0; i < 4; ++i) {
            int mm = lst[i0 + i];                  // padded alloc: safe overread
            bool ok = (i0 + i) < n;
            idx[i] = ok ? mm : 0;
            wg[i] = ok ? ((mm < NK) ? cntFS[b * NK + mm] : 1.0f) : 0.0f;
        }
        float4 xv[4];
#pragma unroll
        for (int i = 0; i < 4; ++i) {
            int mm = idx[i];
            const float4* drow = (mm < NK)
                ? (const float4*)(memFS + ((size_t)b * NK + mm) * ND)
                : (const float4*)(V + (((size_t)b * NT + t) * NN + (mm - NK)) * (size_t)ND);
            xv[i] = drow[c * 64 + lane];
        }
#pragma unroll
        for (int i = 0; i < 4; ++i) {
            sumw += wg[i];
            acc.x += wg[i] * xv[i].x; acc.y += wg[i] * xv[i].y;
            acc.z += wg[i] * xv[i].z; acc.w += wg[i] * xv[i].w;
        }
    }
    float4 vv;
    if (sumw < 1e-6f) {
        vv = ((const float4*)(Cen + (size_t)row * ND))[c * 64 + lane];
    } else {
        float inv = 1.0f / (sumw + 1e-8f);
        vv.x = acc.x * inv; vv.y = acc.y * inv; vv.z = acc.z * inv; vv.w = acc.w * inv;
    }
    ((float4*)(Cout + (size_t)row * ND))[c * 64 + lane] = vv;
    f16x4 h, lo;
    h[0] = (f16)vv.x; lo[0] = (f16)(vv.x - (float)h[0]);
    h[1] = (f16)vv.y; lo[1] = (f16)(vv.y - (float)h[1]);
    h[2] = (f16)vv.z; lo[2] = (f16)(vv.z - (float)h[2]);
    h[3] = (f16)vv.w; lo[3] = (f16)(vv.w - (float)h[3]);
    ((f16x4*)(outH + ((size_t)b * outStride + k) * ND))[c * 64 + lane] = h;
    ((f16x4*)(outL + ((size_t)b * outStride + k) * ND))[c * 64 + lane] = lo;
    float s2 = vv.x * vv.x + vv.y * vv.y + vv.z * vv.z + vv.w * vv.w;
#pragma unroll
    for (int off = 32; off; off >>= 1) s2 += __shfl_xor(s2, off);
    if (lane == 0) cnP[row * 3 + c] = s2;
    if (lane == 0 && c == 0) cntOut[row] = sumw;
}

// ---------------- host ----------------
extern "C" void kernel_launch(void* const* d_in, const int* in_sizes, int n_in,
                              void* d_out, int out_size, void* d_ws, size_t ws_size,
                              hipStream_t stream) {
    const float* V = (const float*)d_in[0];
    float* out = (float*)d_out;
    char* p = (char*)d_ws;
    auto take = [&](size_t bytes) { char* r = p; p += (bytes + 255) & ~(size_t)255; return r; };
    const size_t memB = (size_t)NB * NK * ND * 4;
    float* mem0 = (float*)take(memB);
    float* mem1 = (float*)take(memB);
    float* cnt0 = (float*)take(NB * NK * 4);
    float* cnt1 = (float*)take(NB * NK * 4);
    float* cntS = (float*)take(NB * NK * 4);
    float* cnP  = (float*)take(NB * NK * 3 * 4);
    unsigned long long* packed0 = (unsigned long long*)take(NB * NM * 8);
    unsigned long long* packed1 = (unsigned long long*)take(NB * NM * 8);
    int2* cbBuf  = (int2*)take(NB * NK * 8);
    int*  lstIdx = (int*)take(NB * NM * 4 + 64);    // +pad for group-of-4 overread
    f16* dataH = (f16*)take((size_t)NB * NM * ND * 2);
    f16* dataL = (f16*)take((size_t)NB * NM * ND * 2);
    f16* cenH  = (f16*)take((size_t)NB * NK * ND * 2);
    f16* cenL  = (f16*)take((size_t)NB * NK * ND * 2);

    k_init<<<1024, 256, 0, stream>>>(V, mem0, cnt0, dataH, dataL, cnP, packed0);

    float* mem[2] = {mem0, mem1};
    float* cnt[2] = {cnt0, cnt1};

    for (int f = 0; f < NFRAMES; ++f) {
        int s = f & 1, t = NINIT + f;
        float* mFS = mem[s];
        float* cFS = cnt[s];

        k_prep<<<256, 256, 0, stream>>>(V, t, dataH, dataL);

        // iter 1: centers = memory rows; rows 0..1023 provably self-assign, so
        // score only the 256 new tokens (mOff=1024, 2 M-tiles).
        k_score<<<128, 128, 0, stream>>>(dataH, dataL, dataH, dataL, NM, 1024, 2, cnP, packed0);
        k_lists<<<NB, 1024, 0, stream>>>(packed0, 1, packed1, cbBuf, lstIdx);
        k_update<<<3072, 256, 0, stream>>>(mFS, mFS, V, t, cFS, cbBuf, lstIdx,
                                           out, cntS, cenH, cenL, NK, cnP);

        // iter 2: centers = tmp centers in d_out (split in cenH/L); full score.
        k_score<<<640, 128, 0, stream>>>(dataH, dataL, cenH, cenL, NK, 0, 10, cnP, packed1);
        k_lists<<<NB, 1024, 0, stream>>>(packed1, 0, packed0, cbBuf, lstIdx);
        float* dst = (f == NFRAMES - 1) ? out : mem[1 - s];
        k_update<<<3072, 256, 0, stream>>>(out, mFS, V, t, cFS, cbBuf, lstIdx,
                                           dst, cnt[1 - s], dataH, dataL, NM, cnP);
    }
}

// Round 6
// 3535.837 us; speedup vs baseline: 2.3693x; 1.5453x over previous
//
#include <hip/hip_runtime.h>

#define NB 4
#define NT 32
#define ND 768
#define NK 1024
#define NN 256
#define NINIT 4
#define NFRAMES 28
#define NM 1280

typedef _Float16 f16;
typedef f16 f16x8 __attribute__((ext_vector_type(8)));
typedef f16 f16x4 __attribute__((ext_vector_type(4)));
typedef float f32x4 __attribute__((ext_vector_type(4)));

#define GLOAD_LDS(g, s) __builtin_amdgcn_global_load_lds( \
    (const __attribute__((address_space(1))) void*)(g),   \
    (__attribute__((address_space(3))) void*)(s), 16, 0, 0)

// row-dependent XOR swizzle, closed within a 64-byte row (bits 4-5 only).
__device__ __forceinline__ int swz(int r) { return ((r >> 1) & 3) << 4; }

// ---------------- init: mem copy, counts=1, f16 split, cnorm partials, reset --
__global__ __launch_bounds__(256) void k_init(
    const float* __restrict__ V, float* __restrict__ mem, float* __restrict__ cnt,
    f16* __restrict__ dH, f16* __restrict__ dL,
    float* __restrict__ cnP, unsigned long long* __restrict__ packed0)
{
    int row = blockIdx.x * 4 + (threadIdx.x >> 6);   // 0..4095
    int lane = threadIdx.x & 63;
    int b = row >> 10, k = row & 1023;
    const float4* src = (const float4*)(V + ((size_t)b * NT * NN + k) * ND);
    float4* mrow = (float4*)(mem + (size_t)row * ND);
    f16x4* hrow = (f16x4*)(dH + ((size_t)b * NM + k) * ND);
    f16x4* lrow = (f16x4*)(dL + ((size_t)b * NM + k) * ND);
    float s2 = 0.f;
#pragma unroll
    for (int jj = 0; jj < 3; ++jj) {
        float4 x = src[lane + 64 * jj];
        mrow[lane + 64 * jj] = x;
        f16x4 h, lo;
        h[0] = (f16)x.x; lo[0] = (f16)(x.x - (float)h[0]);
        h[1] = (f16)x.y; lo[1] = (f16)(x.y - (float)h[1]);
        h[2] = (f16)x.z; lo[2] = (f16)(x.z - (float)h[2]);
        h[3] = (f16)x.w; lo[3] = (f16)(x.w - (float)h[3]);
        hrow[lane + 64 * jj] = h;
        lrow[lane + 64 * jj] = lo;
        s2 += x.x * x.x + x.y * x.y + x.z * x.z + x.w * x.w;
    }
#pragma unroll
    for (int off = 32; off; off >>= 1) s2 += __shfl_xor(s2, off);
    if (lane == 0) {
        cnP[row * 3] = s2; cnP[row * 3 + 1] = 0.f; cnP[row * 3 + 2] = 0.f;
        cnt[row] = 1.0f; packed0[(size_t)b * NM + k] = ~0ull;
    }
    if (lane == 1 && k < NN) packed0[(size_t)b * NM + NK + k] = ~0ull;
}

// ---------------- per-frame: split the 256 new tokens ----------------
__global__ __launch_bounds__(256) void k_prep(const float* __restrict__ V, int t,
                                              f16* __restrict__ dH, f16* __restrict__ dL) {
    int row = blockIdx.x * 4 + (threadIdx.x >> 6);  // 0..1023
    int lane = threadIdx.x & 63;
    int b = row >> 8, n = row & 255;
    const float4* src = (const float4*)(V + (((size_t)b * NT + t) * NN + n) * ND);
    f16x4* hrow = (f16x4*)(dH + ((size_t)b * NM + NK + n) * ND);
    f16x4* lrow = (f16x4*)(dL + ((size_t)b * NM + NK + n) * ND);
#pragma unroll
    for (int jj = 0; jj < 3; ++jj) {
        float4 x = src[lane + 64 * jj];
        f16x4 h, lo;
        h[0] = (f16)x.x; lo[0] = (f16)(x.x - (float)h[0]);
        h[1] = (f16)x.y; lo[1] = (f16)(x.y - (float)h[1]);
        h[2] = (f16)x.z; lo[2] = (f16)(x.z - (float)h[2]);
        h[3] = (f16)x.w; lo[3] = (f16)(x.w - (float)h[3]);
        hrow[lane + 64 * jj] = h;
        lrow[lane + 64 * jj] = lo;
    }
}

// ---------------- MFMA score + argmin, double-buffered pipeline -------------
// grid = NB*mTiles*8 blocks x 256 threads. Tile 128(M) x 128(Kcen), 4 waves
// (2x2), each wave 64x64 via 4x4 of 16x16x32 f16 MFMAs, split-f16 3-product.
__global__ __launch_bounds__(256) void k_score(
    const f16* __restrict__ AH, const f16* __restrict__ AL,   // (B, NM, ND)
    const f16* __restrict__ BH, const f16* __restrict__ BL,   // (B, bRows, ND)
    int bRows, int mOff, int mTiles,
    const float* __restrict__ cnP,                            // (B*NK, 3) partials
    unsigned long long* __restrict__ packed)                  // (B, NM)
{
    __shared__ float4 ldsbuf[4096];   // 64 KB: 2 buffers x 32 KB
    char* lds = (char*)ldsbuf;
    int bid = blockIdx.x;
    int cpx = (int)gridDim.x >> 3;
    int sz = (bid & 7) * cpx + (bid >> 3);     // XCD-aware (grid % 8 == 0)
    int pb = mTiles * 8;
    int b = sz / pb;
    int rem = sz - b * pb;
    int mt = rem >> 3, kt = rem & 7;
    int tid = threadIdx.x;
    int w = tid >> 6, l = tid & 63;
    int wm = w >> 1, wk = w & 1;

    // staging: 32 slots of 1 KB (16 rows x 64 B); this wave owns slots w*8..w*8+7
    const char* sp[8];
#pragma unroll
    for (int i = 0; i < 8; ++i) {
        int j = w * 8 + i;
        const f16* base; int r, grow;
        if (j < 8)       { r = 16 * j + (l >> 2);        grow = b * NM + mOff + mt * 128 + r; base = AH; }
        else if (j < 16) { r = 16 * (j - 8) + (l >> 2);  grow = b * NM + mOff + mt * 128 + r; base = AL; }
        else if (j < 24) { r = 16 * (j - 16) + (l >> 2); grow = b * bRows + kt * 128 + r;     base = BH; }
        else             { r = 16 * (j - 24) + (l >> 2); grow = b * bRows + kt * 128 + r;     base = BL; }
        int colB = ((l & 3) * 16) ^ swz(r);              // inverse of read-side swizzle
        sp[i] = (const char*)(base + (size_t)grow * ND) + colB;
    }

    int aoff[4], boff[4];
#pragma unroll
    for (int mi = 0; mi < 4; ++mi) {
        int r = wm * 64 + mi * 16 + (l & 15);
        aoff[mi] = r * 64 + (((l >> 4) * 16) ^ swz(r));
    }
#pragma unroll
    for (int nj = 0; nj < 4; ++nj) {
        int r = wk * 64 + nj * 16 + (l & 15);
        boff[nj] = 16384 + r * 64 + (((l >> 4) * 16) ^ swz(r));
    }

    f32x4 acc[4][4] = {};

#define STAGE(bufbase)                                         \
    _Pragma("unroll")                                          \
    for (int i = 0; i < 8; ++i) {                              \
        GLOAD_LDS(sp[i], lds + (bufbase) + (w * 8 + i) * 1024);\
        sp[i] += 64;                                           \
    }

    STAGE(0);                                      // prologue: chunk 0 -> buf0
    for (int c = 0; c < 24; ++c) {
        int cur = (c & 1) << 15;
        if (c < 23) {
            STAGE(cur ^ 32768);                    // chunk c+1 -> other buffer
            asm volatile("s_waitcnt vmcnt(8)" ::: "memory");   // chunk c landed
        } else {
            asm volatile("s_waitcnt vmcnt(0)" ::: "memory");
        }
        __builtin_amdgcn_s_barrier();
        __builtin_amdgcn_sched_barrier(0);
        f16x8 ah[4], al[4], bh[4], bl[4];
#pragma unroll
        for (int mi = 0; mi < 4; ++mi) {
            ah[mi] = *(const f16x8*)(lds + cur + aoff[mi]);
            al[mi] = *(const f16x8*)(lds + cur + 8192 + aoff[mi]);
        }
#pragma unroll
        for (int nj = 0; nj < 4; ++nj) {
            bh[nj] = *(const f16x8*)(lds + cur + boff[nj]);
            bl[nj] = *(const f16x8*)(lds + cur + 8192 + boff[nj]);
        }
#pragma unroll
        for (int mi = 0; mi < 4; ++mi)
#pragma unroll
            for (int nj = 0; nj < 4; ++nj) {
                acc[mi][nj] = __builtin_amdgcn_mfma_f32_16x16x32_f16(ah[mi], bh[nj], acc[mi][nj], 0, 0, 0);
                acc[mi][nj] = __builtin_amdgcn_mfma_f32_16x16x32_f16(ah[mi], bl[nj], acc[mi][nj], 0, 0, 0);
                acc[mi][nj] = __builtin_amdgcn_mfma_f32_16x16x32_f16(al[mi], bh[nj], acc[mi][nj], 0, 0, 0);
            }
        __builtin_amdgcn_sched_barrier(0);
        __builtin_amdgcn_s_barrier();              // all reads done before re-stage
    }

    int colb = kt * 128 + wk * 64 + (l & 15);
    float cn[4];
#pragma unroll
    for (int nj = 0; nj < 4; ++nj) {
        int kc = b * NK + colb + nj * 16;
        cn[nj] = cnP[kc * 3] + cnP[kc * 3 + 1] + cnP[kc * 3 + 2];
    }
    size_t prow = (size_t)b * NM + mOff + mt * 128 + wm * 64 + (l >> 4) * 4;
#pragma unroll
    for (int mi = 0; mi < 4; ++mi) {
#pragma unroll
        for (int rg = 0; rg < 4; ++rg) {
            float bv = 1e30f; int bi = 0;
#pragma unroll
            for (int nj = 0; nj < 4; ++nj) {
                float s = cn[nj] - 2.0f * acc[mi][nj][rg];
                int ki = colb + nj * 16;
                if (s < bv) { bv = s; bi = ki; }
            }
#pragma unroll
            for (int off = 1; off < 16; off <<= 1) {
                float ov = __shfl_xor(bv, off);
                int   oi = __shfl_xor(bi, off);
                if (ov < bv || (ov == bv && oi < bi)) { bv = ov; bi = oi; }
            }
            if ((l & 15) == 0) {
                unsigned u = __float_as_uint(bv);
                unsigned key = (u >> 31) ? ~u : (u | 0x80000000u);
                atomicMin(&packed[prow + mi * 16 + rg],
                          ((unsigned long long)key << 32) | (unsigned)bi);
            }
        }
    }
}

// ---------------- build CSR lists + position->center map + reset other ------
__global__ __launch_bounds__(1024) void k_lists(
    const unsigned long long* __restrict__ packed, int selfSeed,
    unsigned long long* __restrict__ packedOther,
    int2* __restrict__ cb, int* __restrict__ lstIdx, int* __restrict__ ctrOf)
{
    __shared__ int cntL[NK];
    __shared__ int scanA[NK];
    __shared__ int cursor[NK];
    __shared__ int aSh[NM];
    int b = blockIdx.x, tid = threadIdx.x;
    cntL[tid] = 0;
    __syncthreads();
    for (int m = tid; m < NM; m += 1024) {
        int a;
        if (selfSeed && m < NK) a = m;   // iter1: data row m IS center m
        else a = (int)(unsigned)(packed[(size_t)b * NM + m] & 0xffffffffull);
        aSh[m] = a;
        atomicAdd(&cntL[a], 1);
        packedOther[(size_t)b * NM + m] = ~0ull;
    }
    __syncthreads();
    int v = cntL[tid];
    scanA[tid] = v;
    __syncthreads();
#pragma unroll
    for (int off = 1; off < 1024; off <<= 1) {
        int add = (tid >= off) ? scanA[tid - off] : 0;
        __syncthreads();
        scanA[tid] += add;
        __syncthreads();
    }
    int base = scanA[tid] - v;   // exclusive
    cursor[tid] = base;
    cb[b * NK + tid] = make_int2(v, base);
    __syncthreads();
    for (int m = tid; m < NM; m += 1024) {
        int a = aSh[m];
        int pos = atomicAdd(&cursor[a], 1);
        lstIdx[(size_t)b * NM + pos] = m;
        ctrOf[(size_t)b * NM + pos] = a;
    }
}

// ---------------- stage A: per-8-position segment partial sums --------------
// wave per (b, segment of 8 positions, 256-dim chunk): gathers 8 rows with
// full ILP, computes per-run (contiguous same-center) weighted partial sums,
// flushes to part[lastPosOfRun]. Deterministic, balanced.
__global__ __launch_bounds__(256) void k_part(
    const float* __restrict__ memFS, const float* __restrict__ V, int t,
    const float* __restrict__ cntFS,
    const int* __restrict__ lstIdx, const int* __restrict__ ctrOf,
    float* __restrict__ part, float* __restrict__ partW)
{
    int g = blockIdx.x * 4 + (threadIdx.x >> 6);   // 0..1919
    int l = threadIdx.x & 63;
    int b = g / 480;
    int rem = g - b * 480;
    int seg = rem / 3, c = rem - seg * 3;
    int pos0 = seg * 8;
    const int* li = lstIdx + (size_t)b * NM;
    const int* co = ctrOf + (size_t)b * NM;
    int ctr[8]; float wg[8]; float4 xv[8];
#pragma unroll
    for (int i = 0; i < 8; ++i) {
        int p = pos0 + i;
        ctr[i] = co[p];
        int mm = li[p];
        wg[i] = (mm < NK) ? cntFS[b * NK + mm] : 1.0f;
        const float4* dr = (mm < NK)
            ? (const float4*)(memFS + ((size_t)b * NK + mm) * ND)
            : (const float4*)(V + (((size_t)b * NT + t) * NN + (mm - NK)) * (size_t)ND);
        xv[i] = dr[c * 64 + l];
    }
    float4 acc; float sw; int cur = ctr[0];
    acc.x = wg[0] * xv[0].x; acc.y = wg[0] * xv[0].y;
    acc.z = wg[0] * xv[0].z; acc.w = wg[0] * xv[0].w;
    sw = wg[0];
#pragma unroll
    for (int i = 1; i < 8; ++i) {
        if (ctr[i] != cur) {   // wave-uniform branch
            int e = pos0 + i - 1;
            ((float4*)(part + ((size_t)b * NM + e) * ND))[c * 64 + l] = acc;
            if (c == 0 && l == 0) partW[b * NM + e] = sw;
            cur = ctr[i];
            acc.x = wg[i] * xv[i].x; acc.y = wg[i] * xv[i].y;
            acc.z = wg[i] * xv[i].z; acc.w = wg[i] * xv[i].w;
            sw = wg[i];
        } else {
            acc.x += wg[i] * xv[i].x; acc.y += wg[i] * xv[i].y;
            acc.z += wg[i] * xv[i].z; acc.w += wg[i] * xv[i].w;
            sw += wg[i];
        }
    }
    int e = pos0 + 7;
    ((float4*)(part + ((size_t)b * NM + e) * ND))[c * 64 + l] = acc;
    if (c == 0 && l == 0) partW[b * NM + e] = sw;
}

// ---------------- stage B: combine segment partials, write center ----------
__global__ __launch_bounds__(256) void k_upd(
    const float* __restrict__ Cen,
    const int2* __restrict__ cb,
    const float* __restrict__ part, const float* __restrict__ partW,
    float* __restrict__ Cout, float* __restrict__ cntOut,
    f16* __restrict__ outH, f16* __restrict__ outL, int outStride,
    float* __restrict__ cnP)
{
    int g = blockIdx.x * 4 + (threadIdx.x >> 6);   // 0..12287
    int lane = threadIdx.x & 63;
    int row = g / 3, c = g - row * 3;              // row = b*NK+k, chunk c
    int b = row >> 10, k = row & 1023;
    int2 cnb = cb[row];
    int n = cnb.x, base = cnb.y;
    float4 acc = {0.f, 0.f, 0.f, 0.f};
    float sumw = 0.f;
    if (n > 0) {
        int last = base + n - 1;
        int s1 = last >> 3;
        for (int s = base >> 3; s <= s1; ++s) {    // streamed, independent loads
            int e = (8 * s + 7 < last) ? (8 * s + 7) : last;
            float4 x = ((const float4*)(part + ((size_t)b * NM + e) * ND))[c * 64 + lane];
            acc.x += x.x; acc.y += x.y; acc.z += x.z; acc.w += x.w;
            sumw += partW[b * NM + e];
        }
    }
    float4 vv;
    if (sumw < 1e-6f) {
        vv = ((const float4*)(Cen + (size_t)row * ND))[c * 64 + lane];
        sumw = (n > 0) ? sumw : 0.f;
    } else {
        float inv = 1.0f / (sumw + 1e-8f);
        vv.x = acc.x * inv; vv.y = acc.y * inv; vv.z = acc.z * inv; vv.w = acc.w * inv;
    }
    ((float4*)(Cout + (size_t)row * ND))[c * 64 + lane] = vv;
    f16x4 h, lo;
    h[0] = (f16)vv.x; lo[0] = (f16)(vv.x - (float)h[0]);
    h[1] = (f16)vv.y; lo[1] = (f16)(vv.y - (float)h[1]);
    h[2] = (f16)vv.z; lo[2] = (f16)(vv.z - (float)h[2]);
    h[3] = (f16)vv.w; lo[3] = (f16)(vv.w - (float)h[3]);
    ((f16x4*)(outH + ((size_t)b * outStride + k) * ND))[c * 64 + lane] = h;
    ((f16x4*)(outL + ((size_t)b * outStride + k) * ND))[c * 64 + lane] = lo;
    float s2 = vv.x * vv.x + vv.y * vv.y + vv.z * vv.z + vv.w * vv.w;
#pragma unroll
    for (int off = 32; off; off >>= 1) s2 += __shfl_xor(s2, off);
    if (lane == 0) cnP[row * 3 + c] = s2;
    if (lane == 0 && c == 0) cntOut[row] = sumw;
}

// ---------------- host ----------------
extern "C" void kernel_launch(void* const* d_in, const int* in_sizes, int n_in,
                              void* d_out, int out_size, void* d_ws, size_t ws_size,
                              hipStream_t stream) {
    const float* V = (const float*)d_in[0];
    float* out = (float*)d_out;
    char* p = (char*)d_ws;
    auto take = [&](size_t bytes) { char* r = p; p += (bytes + 255) & ~(size_t)255; return r; };
    const size_t memB = (size_t)NB * NK * ND * 4;
    float* mem0 = (float*)take(memB);
    float* mem1 = (float*)take(memB);
    float* cnt0 = (float*)take(NB * NK * 4);
    float* cnt1 = (float*)take(NB * NK * 4);
    float* cntS = (float*)take(NB * NK * 4);
    float* cnP  = (float*)take(NB * NK * 3 * 4);
    unsigned long long* packed0 = (unsigned long long*)take(NB * NM * 8);
    unsigned long long* packed1 = (unsigned long long*)take(NB * NM * 8);
    int2* cbBuf  = (int2*)take(NB * NK * 8);
    int*  lstIdx = (int*)take(NB * NM * 4);
    int*  ctrOf  = (int*)take(NB * NM * 4);
    float* partW = (float*)take(NB * NM * 4);
    float* partB = (float*)take((size_t)NB * NM * ND * 4);
    f16* dataH = (f16*)take((size_t)NB * NM * ND * 2);
    f16* dataL = (f16*)take((size_t)NB * NM * ND * 2);
    f16* cenH  = (f16*)take((size_t)NB * NK * ND * 2);
    f16* cenL  = (f16*)take((size_t)NB * NK * ND * 2);

    k_init<<<1024, 256, 0, stream>>>(V, mem0, cnt0, dataH, dataL, cnP, packed0);

    float* mem[2] = {mem0, mem1};
    float* cnt[2] = {cnt0, cnt1};

    for (int f = 0; f < NFRAMES; ++f) {
        int s = f & 1, t = NINIT + f;
        float* mFS = mem[s];
        float* cFS = cnt[s];

        k_prep<<<256, 256, 0, stream>>>(V, t, dataH, dataL);

        // iter 1: centers = memory rows; rows 0..1023 provably self-assign ->
        // score only the 256 new tokens (mOff=1024, mTiles=2, kTiles=8).
        k_score<<<64, 256, 0, stream>>>(dataH, dataL, dataH, dataL, NM, 1024, 2, cnP, packed0);
        k_lists<<<NB, 1024, 0, stream>>>(packed0, 1, packed1, cbBuf, lstIdx, ctrOf);
        k_part<<<480, 256, 0, stream>>>(mFS, V, t, cFS, lstIdx, ctrOf, partB, partW);
        k_upd<<<3072, 256, 0, stream>>>(mFS, cbBuf, partB, partW,
                                        out, cntS, cenH, cenL, NK, cnP);

        // iter 2: centers = tmp centers in d_out (split in cenH/L); full score.
        k_score<<<320, 256, 0, stream>>>(dataH, dataL, cenH, cenL, NK, 0, 10, cnP, packed1);
        k_lists<<<NB, 1024, 0, stream>>>(packed1, 0, packed0, cbBuf, lstIdx, ctrOf);
        k_part<<<480, 256, 0, stream>>>(mFS, V, t, cFS, lstIdx, ctrOf, partB, partW);
        float* dst = (f == NFRAMES - 1) ? out : mem[1 - s];
        k_upd<<<3072, 256, 0, stream>>>(out, cbBuf, partB, partW,
                                        dst, cnt[1 - s], dataH, dataL, NM, cnP);
    }
}

// Round 7
// 3463.796 us; speedup vs baseline: 2.4186x; 1.0208x over previous
//
#include <hip/hip_runtime.h>

#define NB 4
#define NT 32
#define ND 768
#define NK 1024
#define NN 256
#define NINIT 4
#define NFRAMES 28
#define NM 1280

typedef _Float16 f16;
typedef f16 f16x8 __attribute__((ext_vector_type(8)));
typedef f16 f16x4 __attribute__((ext_vector_type(4)));
typedef float f32x4 __attribute__((ext_vector_type(4)));

#define GLOAD_LDS(g, s) __builtin_amdgcn_global_load_lds( \
    (const __attribute__((address_space(1))) void*)(g),   \
    (__attribute__((address_space(3))) void*)(s), 16, 0, 0)

// row-dependent XOR swizzle, closed within a 64-byte row (bits 4-5 only).
__device__ __forceinline__ int swz(int r) { return ((r >> 1) & 3) << 4; }

// ---------------- init: mem copy, counts=1, f16 split, cnorm partials, reset --
__global__ __launch_bounds__(256) void k_init(
    const float* __restrict__ V, float* __restrict__ mem, float* __restrict__ cnt,
    f16* __restrict__ dH, f16* __restrict__ dL,
    float* __restrict__ cnP, unsigned long long* __restrict__ packed0)
{
    int row = blockIdx.x * 4 + (threadIdx.x >> 6);   // 0..4095
    int lane = threadIdx.x & 63;
    int b = row >> 10, k = row & 1023;
    const float4* src = (const float4*)(V + ((size_t)b * NT * NN + k) * ND);
    float4* mrow = (float4*)(mem + (size_t)row * ND);
    f16x4* hrow = (f16x4*)(dH + ((size_t)b * NM + k) * ND);
    f16x4* lrow = (f16x4*)(dL + ((size_t)b * NM + k) * ND);
    float s2 = 0.f;
#pragma unroll
    for (int jj = 0; jj < 3; ++jj) {
        float4 x = src[lane + 64 * jj];
        mrow[lane + 64 * jj] = x;
        f16x4 h, lo;
        h[0] = (f16)x.x; lo[0] = (f16)(x.x - (float)h[0]);
        h[1] = (f16)x.y; lo[1] = (f16)(x.y - (float)h[1]);
        h[2] = (f16)x.z; lo[2] = (f16)(x.z - (float)h[2]);
        h[3] = (f16)x.w; lo[3] = (f16)(x.w - (float)h[3]);
        hrow[lane + 64 * jj] = h;
        lrow[lane + 64 * jj] = lo;
        s2 += x.x * x.x + x.y * x.y + x.z * x.z + x.w * x.w;
    }
#pragma unroll
    for (int off = 32; off; off >>= 1) s2 += __shfl_xor(s2, off);
    if (lane == 0) {
        cnP[row * 3] = s2; cnP[row * 3 + 1] = 0.f; cnP[row * 3 + 2] = 0.f;
        cnt[row] = 1.0f; packed0[(size_t)b * NM + k] = ~0ull;
    }
    if (lane == 1 && k < NN) packed0[(size_t)b * NM + NK + k] = ~0ull;
}

// ---------------- per-frame: split the 256 new tokens ----------------
__global__ __launch_bounds__(256) void k_prep(const float* __restrict__ V, int t,
                                              f16* __restrict__ dH, f16* __restrict__ dL) {
    int row = blockIdx.x * 4 + (threadIdx.x >> 6);  // 0..1023
    int lane = threadIdx.x & 63;
    int b = row >> 8, n = row & 255;
    const float4* src = (const float4*)(V + (((size_t)b * NT + t) * NN + n) * ND);
    f16x4* hrow = (f16x4*)(dH + ((size_t)b * NM + NK + n) * ND);
    f16x4* lrow = (f16x4*)(dL + ((size_t)b * NM + NK + n) * ND);
#pragma unroll
    for (int jj = 0; jj < 3; ++jj) {
        float4 x = src[lane + 64 * jj];
        f16x4 h, lo;
        h[0] = (f16)x.x; lo[0] = (f16)(x.x - (float)h[0]);
        h[1] = (f16)x.y; lo[1] = (f16)(x.y - (float)h[1]);
        h[2] = (f16)x.z; lo[2] = (f16)(x.z - (float)h[2]);
        h[3] = (f16)x.w; lo[3] = (f16)(x.w - (float)h[3]);
        hrow[lane + 64 * jj] = h;
        lrow[lane + 64 * jj] = lo;
    }
}

// ---------------- MFMA score + argmin, split-D 8-wave blocks ----------------
// Block tile MT(M) x 64(Kcen), 8 waves = 4 output quadrants x 2 D-halves.
// Waves 0-3: D [0,384); waves 4-7: D [384,768). Each half has its own LDS
// region (single-buffered). After the 12-chunk loop, half-1 waves push acc
// through LDS and half-0 waves combine + do the argmin epilogue.
template<int MT>
__global__ __launch_bounds__(512) void k_score(
    const f16* __restrict__ AH, const f16* __restrict__ AL,   // (B, NM, ND)
    const f16* __restrict__ BH, const f16* __restrict__ BL,   // (B, bRows, ND)
    int bRows, int mOff, int mTiles,
    const float* __restrict__ cnP,                            // (B*NK, 3) partials
    unsigned long long* __restrict__ packed)                  // (B, NM)
{
    constexpr int FM = MT / 32;            // A frags per wave (quadrant rows / 16)
    constexpr int QROWS = MT / 2;          // rows per quadrant
    constexpr int ASL = MT / 16;           // 1KB slots for AH (and AL) per half
    constexpr int SLOTS = 2 * ASL + 8;     // slots per half region
    constexpr int SPW = SLOTS / 4;         // staging slots per wave
    constexpr int RSZ = SLOTS * 1024;      // region bytes

    __shared__ float4 ldsbuf[SLOTS * 128]; // 2 * RSZ bytes
    char* lds = (char*)ldsbuf;

    int bid = blockIdx.x;
    int cpx = (int)gridDim.x >> 3;
    int sz = (bid & 7) * cpx + (bid >> 3);     // XCD-aware (grid % 8 == 0)
    int pb = mTiles * 16;
    int b = sz / pb;
    int rem = sz - b * pb;
    int mt = rem >> 4, kt = rem & 15;
    int tid = threadIdx.x;
    int w = tid >> 6, l = tid & 63;
    int h = w >> 2, q = w & 3;
    int wm = q >> 1, wk = q & 1;
    const int REG = h * RSZ;

    // staging source pointers: wave stages SPW slots into its own region
    const char* sp[SPW];
#pragma unroll
    for (int i = 0; i < SPW; ++i) {
        int slot = q * SPW + i;
        const f16* base; int r, grow;
        if (slot < ASL)            { r = slot * 16 + (l >> 2);             grow = b * NM + mOff + mt * MT + r; base = AH; }
        else if (slot < 2 * ASL)   { r = (slot - ASL) * 16 + (l >> 2);     grow = b * NM + mOff + mt * MT + r; base = AL; }
        else if (slot < 2*ASL + 4) { r = (slot - 2*ASL) * 16 + (l >> 2);   grow = b * bRows + kt * 64 + r;     base = BH; }
        else                       { r = (slot - 2*ASL - 4) * 16 + (l >> 2); grow = b * bRows + kt * 64 + r;   base = BL; }
        int colB = ((l & 3) * 16) ^ swz(r);              // inverse of read-side swizzle
        sp[i] = (const char*)(base + (size_t)grow * ND) + h * 768 + colB;
    }

    // fragment read offsets (within own region)
    int aoffH[FM], aoffL[FM], boffH[2], boffL[2];
#pragma unroll
    for (int mi = 0; mi < FM; ++mi) {
        int r = wm * QROWS + mi * 16 + (l & 15);
        int off = r * 64 + (((l >> 4) * 16) ^ swz(r));
        aoffH[mi] = REG + off;
        aoffL[mi] = REG + ASL * 1024 + off;
    }
#pragma unroll
    for (int nj = 0; nj < 2; ++nj) {
        int rB = wk * 32 + nj * 16 + (l & 15);
        int off = rB * 64 + (((l >> 4) * 16) ^ swz(rB));
        boffH[nj] = REG + 2 * ASL * 1024 + off;
        boffL[nj] = REG + 2 * ASL * 1024 + 4096 + off;
    }

    f32x4 acc[FM][2] = {};

    for (int c = 0; c < 12; ++c) {
#pragma unroll
        for (int i = 0; i < SPW; ++i) {
            GLOAD_LDS(sp[i], lds + REG + (q * SPW + i) * 1024);
            sp[i] += 64;
        }
        __syncthreads();
        f16x8 ah[FM], al[FM], bh[2], bl[2];
#pragma unroll
        for (int mi = 0; mi < FM; ++mi) {
            ah[mi] = *(const f16x8*)(lds + aoffH[mi]);
            al[mi] = *(const f16x8*)(lds + aoffL[mi]);
        }
#pragma unroll
        for (int nj = 0; nj < 2; ++nj) {
            bh[nj] = *(const f16x8*)(lds + boffH[nj]);
            bl[nj] = *(const f16x8*)(lds + boffL[nj]);
        }
#pragma unroll
        for (int mi = 0; mi < FM; ++mi)
#pragma unroll
            for (int nj = 0; nj < 2; ++nj) {
                acc[mi][nj] = __builtin_amdgcn_mfma_f32_16x16x32_f16(ah[mi], bh[nj], acc[mi][nj], 0, 0, 0);
                acc[mi][nj] = __builtin_amdgcn_mfma_f32_16x16x32_f16(ah[mi], bl[nj], acc[mi][nj], 0, 0, 0);
                acc[mi][nj] = __builtin_amdgcn_mfma_f32_16x16x32_f16(al[mi], bh[nj], acc[mi][nj], 0, 0, 0);
            }
        __syncthreads();
    }

    // combine D-halves through LDS (reuses staging space; all reads drained)
    int coff = q * (QROWS * 128) + l * 16;
    if (h == 1) {
#pragma unroll
        for (int mi = 0; mi < FM; ++mi)
#pragma unroll
            for (int nj = 0; nj < 2; ++nj)
                *(f32x4*)(lds + coff + (mi * 2 + nj) * 1024) = acc[mi][nj];
    }
    __syncthreads();
    if (h != 0) return;
#pragma unroll
    for (int mi = 0; mi < FM; ++mi)
#pragma unroll
        for (int nj = 0; nj < 2; ++nj)
            acc[mi][nj] += *(const f32x4*)(lds + coff + (mi * 2 + nj) * 1024);

    // epilogue: score = cnorm - 2*dot; per-row argmin -> packed atomicMin
    int colb = kt * 64 + wk * 32 + (l & 15);
    float cn[2];
#pragma unroll
    for (int nj = 0; nj < 2; ++nj) {
        int kc = b * NK + colb + nj * 16;
        cn[nj] = cnP[kc * 3] + cnP[kc * 3 + 1] + cnP[kc * 3 + 2];
    }
    size_t prow = (size_t)b * NM + mOff + mt * MT + wm * QROWS + (l >> 4) * 4;
#pragma unroll
    for (int mi = 0; mi < FM; ++mi) {
#pragma unroll
        for (int rg = 0; rg < 4; ++rg) {
            float bv = 1e30f; int bi = 0;
#pragma unroll
            for (int nj = 0; nj < 2; ++nj) {
                float s = cn[nj] - 2.0f * acc[mi][nj][rg];
                int ki = colb + nj * 16;
                if (s < bv) { bv = s; bi = ki; }
            }
#pragma unroll
            for (int off = 1; off < 16; off <<= 1) {
                float ov = __shfl_xor(bv, off);
                int   oi = __shfl_xor(bi, off);
                if (ov < bv || (ov == bv && oi < bi)) { bv = ov; bi = oi; }
            }
            if ((l & 15) == 0) {
                unsigned u = __float_as_uint(bv);
                unsigned key = (u >> 31) ? ~u : (u | 0x80000000u);
                atomicMin(&packed[prow + mi * 16 + rg],
                          ((unsigned long long)key << 32) | (unsigned)bi);
            }
        }
    }
}

// ---------------- build CSR lists + position->center map + reset other ------
__global__ __launch_bounds__(1024) void k_lists(
    const unsigned long long* __restrict__ packed, int selfSeed,
    unsigned long long* __restrict__ packedOther,
    int2* __restrict__ cb, int* __restrict__ lstIdx, int* __restrict__ ctrOf)
{
    __shared__ int cntL[NK];
    __shared__ int wsum[16];
    __shared__ int cursor[NK];
    __shared__ int aSh[NM];
    int b = blockIdx.x, tid = threadIdx.x;
    cntL[tid] = 0;
    __syncthreads();
    for (int m = tid; m < NM; m += 1024) {
        int a;
        if (selfSeed && m < NK) a = m;   // iter1: data row m IS center m
        else a = (int)(unsigned)(packed[(size_t)b * NM + m] & 0xffffffffull);
        aSh[m] = a;
        atomicAdd(&cntL[a], 1);
        packedOther[(size_t)b * NM + m] = ~0ull;
    }
    __syncthreads();
    int v = cntL[tid];
    int lane = tid & 63, wv = tid >> 6;
    int x = v;                           // wave-level inclusive scan
#pragma unroll
    for (int off = 1; off < 64; off <<= 1) {
        int y = __shfl_up(x, off);
        if (lane >= off) x += y;
    }
    if (lane == 63) wsum[wv] = x;
    __syncthreads();
    if (tid < 16) {                      // scan the 16 wave totals
        int s = wsum[tid];
        int e = s;
#pragma unroll
        for (int off = 1; off < 16; off <<= 1) {
            int y = __shfl_up(e, off, 16);
            if (tid >= off) e += y;
        }
        wsum[tid] = e - s;               // exclusive wave prefix
    }
    __syncthreads();
    int base = x + wsum[wv] - v;         // global exclusive prefix
    cursor[tid] = base;
    cb[b * NK + tid] = make_int2(v, base);
    __syncthreads();
    for (int m = tid; m < NM; m += 1024) {
        int a = aSh[m];
        int pos = atomicAdd(&cursor[a], 1);
        lstIdx[(size_t)b * NM + pos] = m;
        ctrOf[(size_t)b * NM + pos] = a;
    }
}

// ---------------- stage A: per-8-position segment partial sums --------------
__global__ __launch_bounds__(256) void k_part(
    const float* __restrict__ memFS, const float* __restrict__ V, int t,
    const float* __restrict__ cntFS,
    const int* __restrict__ lstIdx, const int* __restrict__ ctrOf,
    float* __restrict__ part, float* __restrict__ partW)
{
    int g = blockIdx.x * 4 + (threadIdx.x >> 6);   // 0..1919
    int l = threadIdx.x & 63;
    int b = g / 480;
    int rem = g - b * 480;
    int seg = rem / 3, c = rem - seg * 3;
    int pos0 = seg * 8;
    const int* li = lstIdx + (size_t)b * NM;
    const int* co = ctrOf + (size_t)b * NM;
    int ctr[8]; float wg[8]; float4 xv[8];
#pragma unroll
    for (int i = 0; i < 8; ++i) {
        int p = pos0 + i;
        ctr[i] = co[p];
        int mm = li[p];
        wg[i] = (mm < NK) ? cntFS[b * NK + mm] : 1.0f;
        const float4* dr = (mm < NK)
            ? (const float4*)(memFS + ((size_t)b * NK + mm) * ND)
            : (const float4*)(V + (((size_t)b * NT + t) * NN + (mm - NK)) * (size_t)ND);
        xv[i] = dr[c * 64 + l];
    }
    float4 acc; float sw; int cur = ctr[0];
    acc.x = wg[0] * xv[0].x; acc.y = wg[0] * xv[0].y;
    acc.z = wg[0] * xv[0].z; acc.w = wg[0] * xv[0].w;
    sw = wg[0];
#pragma unroll
    for (int i = 1; i < 8; ++i) {
        if (ctr[i] != cur) {   // wave-uniform branch
            int e = pos0 + i - 1;
            ((float4*)(part + ((size_t)b * NM + e) * ND))[c * 64 + l] = acc;
            if (c == 0 && l == 0) partW[b * NM + e] = sw;
            cur = ctr[i];
            acc.x = wg[i] * xv[i].x; acc.y = wg[i] * xv[i].y;
            acc.z = wg[i] * xv[i].z; acc.w = wg[i] * xv[i].w;
            sw = wg[i];
        } else {
            acc.x += wg[i] * xv[i].x; acc.y += wg[i] * xv[i].y;
            acc.z += wg[i] * xv[i].z; acc.w += wg[i] * xv[i].w;
            sw += wg[i];
        }
    }
    int e = pos0 + 7;
    ((float4*)(part + ((size_t)b * NM + e) * ND))[c * 64 + l] = acc;
    if (c == 0 && l == 0) partW[b * NM + e] = sw;
}

// ---------------- stage B: combine segment partials, write center ----------
__global__ __launch_bounds__(256) void k_upd(
    const float* __restrict__ Cen,
    const int2* __restrict__ cb,
    const float* __restrict__ part, const float* __restrict__ partW,
    float* __restrict__ Cout, float* __restrict__ cntOut,
    f16* __restrict__ outH, f16* __restrict__ outL, int outStride,
    float* __restrict__ cnP)
{
    int g = blockIdx.x * 4 + (threadIdx.x >> 6);   // 0..12287
    int lane = threadIdx.x & 63;
    int row = g / 3, c = g - row * 3;              // row = b*NK+k, chunk c
    int b = row >> 10, k = row & 1023;
    int2 cnb = cb[row];
    int n = cnb.x, base = cnb.y;
    float4 acc = {0.f, 0.f, 0.f, 0.f};
    float sumw = 0.f;
    if (n > 0) {
        int last = base + n - 1;
        int s1 = last >> 3;
        for (int s = base >> 3; s <= s1; ++s) {    // streamed, independent loads
            int e = (8 * s + 7 < last) ? (8 * s + 7) : last;
            float4 x = ((const float4*)(part + ((size_t)b * NM + e) * ND))[c * 64 + lane];
            acc.x += x.x; acc.y += x.y; acc.z += x.z; acc.w += x.w;
            sumw += partW[b * NM + e];
        }
    }
    float4 vv;
    if (sumw < 1e-6f) {
        vv = ((const float4*)(Cen + (size_t)row * ND))[c * 64 + lane];
        sumw = (n > 0) ? sumw : 0.f;
    } else {
        float inv = 1.0f / (sumw + 1e-8f);
        vv.x = acc.x * inv; vv.y = acc.y * inv; vv.z = acc.z * inv; vv.w = acc.w * inv;
    }
    ((float4*)(Cout + (size_t)row * ND))[c * 64 + lane] = vv;
    f16x4 h, lo;
    h[0] = (f16)vv.x; lo[0] = (f16)(vv.x - (float)h[0]);
    h[1] = (f16)vv.y; lo[1] = (f16)(vv.y - (float)h[1]);
    h[2] = (f16)vv.z; lo[2] = (f16)(vv.z - (float)h[2]);
    h[3] = (f16)vv.w; lo[3] = (f16)(vv.w - (float)h[3]);
    ((f16x4*)(outH + ((size_t)b * outStride + k) * ND))[c * 64 + lane] = h;
    ((f16x4*)(outL + ((size_t)b * outStride + k) * ND))[c * 64 + lane] = lo;
    float s2 = vv.x * vv.x + vv.y * vv.y + vv.z * vv.z + vv.w * vv.w;
#pragma unroll
    for (int off = 32; off; off >>= 1) s2 += __shfl_xor(s2, off);
    if (lane == 0) cnP[row * 3 + c] = s2;
    if (lane == 0 && c == 0) cntOut[row] = sumw;
}

// ---------------- host ----------------
extern "C" void kernel_launch(void* const* d_in, const int* in_sizes, int n_in,
                              void* d_out, int out_size, void* d_ws, size_t ws_size,
                              hipStream_t stream) {
    const float* V = (const float*)d_in[0];
    float* out = (float*)d_out;
    char* p = (char*)d_ws;
    auto take = [&](size_t bytes) { char* r = p; p += (bytes + 255) & ~(size_t)255; return r; };
    const size_t memB = (size_t)NB * NK * ND * 4;
    float* mem0 = (float*)take(memB);
    float* mem1 = (float*)take(memB);
    float* cnt0 = (float*)take(NB * NK * 4);
    float* cnt1 = (float*)take(NB * NK * 4);
    float* cntS = (float*)take(NB * NK * 4);
    float* cnP  = (float*)take(NB * NK * 3 * 4);
    unsigned long long* packed0 = (unsigned long long*)take(NB * NM * 8);
    unsigned long long* packed1 = (unsigned long long*)take(NB * NM * 8);
    int2* cbBuf  = (int2*)take(NB * NK * 8);
    int*  lstIdx = (int*)take(NB * NM * 4);
    int*  ctrOf  = (int*)take(NB * NM * 4);
    float* partW = (float*)take(NB * NM * 4);
    float* partB = (float*)take((size_t)NB * NM * ND * 4);
    f16* dataH = (f16*)take((size_t)NB * NM * ND * 2);
    f16* dataL = (f16*)take((size_t)NB * NM * ND * 2);
    f16* cenH  = (f16*)take((size_t)NB * NK * ND * 2);
    f16* cenL  = (f16*)take((size_t)NB * NK * ND * 2);

    k_init<<<1024, 256, 0, stream>>>(V, mem0, cnt0, dataH, dataL, cnP, packed0);

    float* mem[2] = {mem0, mem1};
    float* cnt[2] = {cnt0, cnt1};

    for (int f = 0; f < NFRAMES; ++f) {
        int s = f & 1, t = NINIT + f;
        float* mFS = mem[s];
        float* cFS = cnt[s];

        k_prep<<<256, 256, 0, stream>>>(V, t, dataH, dataL);

        // iter 1: centers = memory rows; rows 0..1023 provably self-assign ->
        // score only the 256 new tokens (MT=64: 4 mTiles x 16 kTiles x 4 b).
        k_score<64><<<256, 512, 0, stream>>>(dataH, dataL, dataH, dataL, NM, 1024, 4, cnP, packed0);
        k_lists<<<NB, 1024, 0, stream>>>(packed0, 1, packed1, cbBuf, lstIdx, ctrOf);
        k_part<<<480, 256, 0, stream>>>(mFS, V, t, cFS, lstIdx, ctrOf, partB, partW);
        k_upd<<<3072, 256, 0, stream>>>(mFS, cbBuf, partB, partW,
                                        out, cntS, cenH, cenL, NK, cnP);

        // iter 2: centers = tmp centers in d_out (split in cenH/L); full score
        // (MT=128: 10 mTiles x 16 kTiles x 4 b = 640 blocks).
        k_score<128><<<640, 512, 0, stream>>>(dataH, dataL, cenH, cenL, NK, 0, 10, cnP, packed1);
        k_lists<<<NB, 1024, 0, stream>>>(packed1, 0, packed0, cbBuf, lstIdx, ctrOf);
        k_part<<<480, 256, 0, stream>>>(mFS, V, t, cFS, lstIdx, ctrOf, partB, partW);
        float* dst = (f == NFRAMES - 1) ? out : mem[1 - s];
        k_upd<<<3072, 256, 0, stream>>>(out, cbBuf, partB, partW,
                                        dst, cnt[1 - s], dataH, dataL, NM, cnP);
    }
}

// Round 8
// 3123.020 us; speedup vs baseline: 2.6825x; 1.1091x over previous
//
#include <hip/hip_runtime.h>

#define NB 4
#define NT 32
#define ND 768
#define NK 1024
#define NN 256
#define NINIT 4
#define NFRAMES 28
#define NM 1280

typedef _Float16 f16;
typedef f16 f16x8 __attribute__((ext_vector_type(8)));
typedef f16 f16x4 __attribute__((ext_vector_type(4)));
typedef float f32x4 __attribute__((ext_vector_type(4)));

#define GLOAD_LDS(g, s) __builtin_amdgcn_global_load_lds( \
    (const __attribute__((address_space(1))) void*)(g),   \
    (__attribute__((address_space(3))) void*)(s), 16, 0, 0)

// row-dependent XOR swizzle, closed within a 64-byte row (bits 4-5 only).
__device__ __forceinline__ int swz(int r) { return ((r >> 1) & 3) << 4; }

// ---------------- init: mem copy, counts=1, f16 split, cnorm partials, reset --
__global__ __launch_bounds__(256) void k_init(
    const float* __restrict__ V, float* __restrict__ mem, float* __restrict__ cnt,
    f16* __restrict__ dH, f16* __restrict__ dL,
    float* __restrict__ cnP, unsigned long long* __restrict__ packed0)
{
    int row = blockIdx.x * 4 + (threadIdx.x >> 6);   // 0..4095
    int lane = threadIdx.x & 63;
    int b = row >> 10, k = row & 1023;
    const float4* src = (const float4*)(V + ((size_t)b * NT * NN + k) * ND);
    float4* mrow = (float4*)(mem + (size_t)row * ND);
    f16x4* hrow = (f16x4*)(dH + ((size_t)b * NM + k) * ND);
    f16x4* lrow = (f16x4*)(dL + ((size_t)b * NM + k) * ND);
    float s2 = 0.f;
#pragma unroll
    for (int jj = 0; jj < 3; ++jj) {
        float4 x = src[lane + 64 * jj];
        mrow[lane + 64 * jj] = x;
        f16x4 h, lo;
        h[0] = (f16)x.x; lo[0] = (f16)(x.x - (float)h[0]);
        h[1] = (f16)x.y; lo[1] = (f16)(x.y - (float)h[1]);
        h[2] = (f16)x.z; lo[2] = (f16)(x.z - (float)h[2]);
        h[3] = (f16)x.w; lo[3] = (f16)(x.w - (float)h[3]);
        hrow[lane + 64 * jj] = h;
        lrow[lane + 64 * jj] = lo;
        s2 += x.x * x.x + x.y * x.y + x.z * x.z + x.w * x.w;
    }
#pragma unroll
    for (int off = 32; off; off >>= 1) s2 += __shfl_xor(s2, off);
    if (lane == 0) {
        cnP[row * 3] = s2; cnP[row * 3 + 1] = 0.f; cnP[row * 3 + 2] = 0.f;
        cnt[row] = 1.0f; packed0[(size_t)b * NM + k] = ~0ull;
    }
    if (lane == 1 && k < NN) packed0[(size_t)b * NM + NK + k] = ~0ull;
}

// ---------------- per-frame: split the 256 new tokens ----------------
__global__ __launch_bounds__(256) void k_prep(const float* __restrict__ V, int t,
                                              f16* __restrict__ dH, f16* __restrict__ dL) {
    int row = blockIdx.x * 4 + (threadIdx.x >> 6);  // 0..1023
    int lane = threadIdx.x & 63;
    int b = row >> 8, n = row & 255;
    const float4* src = (const float4*)(V + (((size_t)b * NT + t) * NN + n) * ND);
    f16x4* hrow = (f16x4*)(dH + ((size_t)b * NM + NK + n) * ND);
    f16x4* lrow = (f16x4*)(dL + ((size_t)b * NM + NK + n) * ND);
#pragma unroll
    for (int jj = 0; jj < 3; ++jj) {
        float4 x = src[lane + 64 * jj];
        f16x4 h, lo;
        h[0] = (f16)x.x; lo[0] = (f16)(x.x - (float)h[0]);
        h[1] = (f16)x.y; lo[1] = (f16)(x.y - (float)h[1]);
        h[2] = (f16)x.z; lo[2] = (f16)(x.z - (float)h[2]);
        h[3] = (f16)x.w; lo[3] = (f16)(x.w - (float)h[3]);
        hrow[lane + 64 * jj] = h;
        lrow[lane + 64 * jj] = lo;
    }
}

// ---------------- iter1 MFMA score: split-D 8-wave blocks (MT=64) -----------
template<int MT>
__global__ __launch_bounds__(512) void k_score(
    const f16* __restrict__ AH, const f16* __restrict__ AL,   // (B, NM, ND)
    const f16* __restrict__ BH, const f16* __restrict__ BL,   // (B, bRows, ND)
    int bRows, int mOff, int mTiles,
    const float* __restrict__ cnP,                            // (B*NK, 3) partials
    unsigned long long* __restrict__ packed)                  // (B, NM)
{
    constexpr int FM = MT / 32;            // A frags per wave (quadrant rows / 16)
    constexpr int QROWS = MT / 2;          // rows per quadrant
    constexpr int ASL = MT / 16;           // 1KB slots for AH (and AL) per half
    constexpr int SLOTS = 2 * ASL + 8;     // slots per half region
    constexpr int SPW = SLOTS / 4;         // staging slots per wave
    constexpr int RSZ = SLOTS * 1024;      // region bytes

    __shared__ float4 ldsbuf[SLOTS * 128]; // 2 * RSZ bytes
    char* lds = (char*)ldsbuf;

    int bid = blockIdx.x;
    int cpx = (int)gridDim.x >> 3;
    int sz = (bid & 7) * cpx + (bid >> 3);     // XCD-aware (grid % 8 == 0)
    int pb = mTiles * 16;
    int b = sz / pb;
    int rem = sz - b * pb;
    int mt = rem >> 4, kt = rem & 15;
    int tid = threadIdx.x;
    int w = tid >> 6, l = tid & 63;
    int h = w >> 2, q = w & 3;
    int wm = q >> 1, wk = q & 1;
    const int REG = h * RSZ;

    const char* sp[SPW];
#pragma unroll
    for (int i = 0; i < SPW; ++i) {
        int slot = q * SPW + i;
        const f16* base; int r, grow;
        if (slot < ASL)            { r = slot * 16 + (l >> 2);             grow = b * NM + mOff + mt * MT + r; base = AH; }
        else if (slot < 2 * ASL)   { r = (slot - ASL) * 16 + (l >> 2);     grow = b * NM + mOff + mt * MT + r; base = AL; }
        else if (slot < 2*ASL + 4) { r = (slot - 2*ASL) * 16 + (l >> 2);   grow = b * bRows + kt * 64 + r;     base = BH; }
        else                       { r = (slot - 2*ASL - 4) * 16 + (l >> 2); grow = b * bRows + kt * 64 + r;   base = BL; }
        int colB = ((l & 3) * 16) ^ swz(r);              // inverse of read-side swizzle
        sp[i] = (const char*)(base + (size_t)grow * ND) + h * 768 + colB;
    }

    int aoffH[FM], aoffL[FM], boffH[2], boffL[2];
#pragma unroll
    for (int mi = 0; mi < FM; ++mi) {
        int r = wm * QROWS + mi * 16 + (l & 15);
        int off = r * 64 + (((l >> 4) * 16) ^ swz(r));
        aoffH[mi] = REG + off;
        aoffL[mi] = REG + ASL * 1024 + off;
    }
#pragma unroll
    for (int nj = 0; nj < 2; ++nj) {
        int rB = wk * 32 + nj * 16 + (l & 15);
        int off = rB * 64 + (((l >> 4) * 16) ^ swz(rB));
        boffH[nj] = REG + 2 * ASL * 1024 + off;
        boffL[nj] = REG + 2 * ASL * 1024 + 4096 + off;
    }

    f32x4 acc[FM][2] = {};

    for (int c = 0; c < 12; ++c) {
#pragma unroll
        for (int i = 0; i < SPW; ++i) {
            GLOAD_LDS(sp[i], lds + REG + (q * SPW + i) * 1024);
            sp[i] += 64;
        }
        __syncthreads();
        f16x8 ah[FM], al[FM], bh[2], bl[2];
#pragma unroll
        for (int mi = 0; mi < FM; ++mi) {
            ah[mi] = *(const f16x8*)(lds + aoffH[mi]);
            al[mi] = *(const f16x8*)(lds + aoffL[mi]);
        }
#pragma unroll
        for (int nj = 0; nj < 2; ++nj) {
            bh[nj] = *(const f16x8*)(lds + boffH[nj]);
            bl[nj] = *(const f16x8*)(lds + boffL[nj]);
        }
#pragma unroll
        for (int mi = 0; mi < FM; ++mi)
#pragma unroll
            for (int nj = 0; nj < 2; ++nj) {
                acc[mi][nj] = __builtin_amdgcn_mfma_f32_16x16x32_f16(ah[mi], bh[nj], acc[mi][nj], 0, 0, 0);
                acc[mi][nj] = __builtin_amdgcn_mfma_f32_16x16x32_f16(ah[mi], bl[nj], acc[mi][nj], 0, 0, 0);
                acc[mi][nj] = __builtin_amdgcn_mfma_f32_16x16x32_f16(al[mi], bh[nj], acc[mi][nj], 0, 0, 0);
            }
        __syncthreads();
    }

    // combine D-halves through LDS
    int coff = q * (QROWS * 128) + l * 16;
    if (h == 1) {
#pragma unroll
        for (int mi = 0; mi < FM; ++mi)
#pragma unroll
            for (int nj = 0; nj < 2; ++nj)
                *(f32x4*)(lds + coff + (mi * 2 + nj) * 1024) = acc[mi][nj];
    }
    __syncthreads();
    if (h != 0) return;
#pragma unroll
    for (int mi = 0; mi < FM; ++mi)
#pragma unroll
        for (int nj = 0; nj < 2; ++nj)
            acc[mi][nj] += *(const f32x4*)(lds + coff + (mi * 2 + nj) * 1024);

    int colb = kt * 64 + wk * 32 + (l & 15);
    float cn[2];
#pragma unroll
    for (int nj = 0; nj < 2; ++nj) {
        int kc = b * NK + colb + nj * 16;
        cn[nj] = cnP[kc * 3] + cnP[kc * 3 + 1] + cnP[kc * 3 + 2];
    }
    size_t prow = (size_t)b * NM + mOff + mt * MT + wm * QROWS + (l >> 4) * 4;
#pragma unroll
    for (int mi = 0; mi < FM; ++mi) {
#pragma unroll
        for (int rg = 0; rg < 4; ++rg) {
            float bv = 1e30f; int bi = 0;
#pragma unroll
            for (int nj = 0; nj < 2; ++nj) {
                float s = cn[nj] - 2.0f * acc[mi][nj][rg];
                int ki = colb + nj * 16;
                if (s < bv) { bv = s; bi = ki; }
            }
#pragma unroll
            for (int off = 1; off < 16; off <<= 1) {
                float ov = __shfl_xor(bv, off);
                int   oi = __shfl_xor(bi, off);
                if (ov < bv || (ov == bv && oi < bi)) { bv = ov; bi = oi; }
            }
            if ((l & 15) == 0) {
                unsigned u = __float_as_uint(bv);
                unsigned key = (u >> 31) ? ~u : (u | 0x80000000u);
                atomicMin(&packed[prow + mi * 16 + rg],
                          ((unsigned long long)key << 32) | (unsigned)bi);
            }
        }
    }
}

// ---------------- iter2 MFMA score: R6 4-wave 128x128 dbuf + counted vmcnt ---
__global__ __launch_bounds__(256) void k_score2(
    const f16* __restrict__ AH, const f16* __restrict__ AL,   // (B, NM, ND)
    const f16* __restrict__ BH, const f16* __restrict__ BL,   // (B, bRows, ND)
    int bRows, int mOff, int mTiles,
    const float* __restrict__ cnP,                            // (B*NK, 3) partials
    unsigned long long* __restrict__ packed)                  // (B, NM)
{
    __shared__ float4 ldsbuf[4096];   // 64 KB: 2 buffers x 32 KB
    char* lds = (char*)ldsbuf;
    int bid = blockIdx.x;
    int cpx = (int)gridDim.x >> 3;
    int sz = (bid & 7) * cpx + (bid >> 3);     // XCD-aware (grid % 8 == 0)
    int pb = mTiles * 8;
    int b = sz / pb;
    int rem = sz - b * pb;
    int mt = rem >> 3, kt = rem & 7;
    int tid = threadIdx.x;
    int w = tid >> 6, l = tid & 63;
    int wm = w >> 1, wk = w & 1;

    const char* sp[8];
#pragma unroll
    for (int i = 0; i < 8; ++i) {
        int j = w * 8 + i;
        const f16* base; int r, grow;
        if (j < 8)       { r = 16 * j + (l >> 2);        grow = b * NM + mOff + mt * 128 + r; base = AH; }
        else if (j < 16) { r = 16 * (j - 8) + (l >> 2);  grow = b * NM + mOff + mt * 128 + r; base = AL; }
        else if (j < 24) { r = 16 * (j - 16) + (l >> 2); grow = b * bRows + kt * 128 + r;     base = BH; }
        else             { r = 16 * (j - 24) + (l >> 2); grow = b * bRows + kt * 128 + r;     base = BL; }
        int colB = ((l & 3) * 16) ^ swz(r);              // inverse of read-side swizzle
        sp[i] = (const char*)(base + (size_t)grow * ND) + colB;
    }

    int aoff[4], boff[4];
#pragma unroll
    for (int mi = 0; mi < 4; ++mi) {
        int r = wm * 64 + mi * 16 + (l & 15);
        aoff[mi] = r * 64 + (((l >> 4) * 16) ^ swz(r));
    }
#pragma unroll
    for (int nj = 0; nj < 4; ++nj) {
        int r = wk * 64 + nj * 16 + (l & 15);
        boff[nj] = 16384 + r * 64 + (((l >> 4) * 16) ^ swz(r));
    }

    f32x4 acc[4][4] = {};

#define STAGE2(bufbase)                                        \
    _Pragma("unroll")                                          \
    for (int i = 0; i < 8; ++i) {                              \
        GLOAD_LDS(sp[i], lds + (bufbase) + (w * 8 + i) * 1024);\
        sp[i] += 64;                                           \
    }

    STAGE2(0);                                     // prologue: chunk 0 -> buf0
    for (int c = 0; c < 24; ++c) {
        int cur = (c & 1) << 15;
        if (c < 23) {
            STAGE2(cur ^ 32768);                   // chunk c+1 -> other buffer
            asm volatile("s_waitcnt vmcnt(8)" ::: "memory");   // chunk c landed
        } else {
            asm volatile("s_waitcnt vmcnt(0)" ::: "memory");
        }
        __builtin_amdgcn_s_barrier();
        __builtin_amdgcn_sched_barrier(0);
        f16x8 ah[4], al[4], bh[4], bl[4];
#pragma unroll
        for (int mi = 0; mi < 4; ++mi) {
            ah[mi] = *(const f16x8*)(lds + cur + aoff[mi]);
            al[mi] = *(const f16x8*)(lds + cur + 8192 + aoff[mi]);
        }
#pragma unroll
        for (int nj = 0; nj < 4; ++nj) {
            bh[nj] = *(const f16x8*)(lds + cur + boff[nj]);
            bl[nj] = *(const f16x8*)(lds + cur + 8192 + boff[nj]);
        }
#pragma unroll
        for (int mi = 0; mi < 4; ++mi)
#pragma unroll
            for (int nj = 0; nj < 4; ++nj) {
                acc[mi][nj] = __builtin_amdgcn_mfma_f32_16x16x32_f16(ah[mi], bh[nj], acc[mi][nj], 0, 0, 0);
                acc[mi][nj] = __builtin_amdgcn_mfma_f32_16x16x32_f16(ah[mi], bl[nj], acc[mi][nj], 0, 0, 0);
                acc[mi][nj] = __builtin_amdgcn_mfma_f32_16x16x32_f16(al[mi], bh[nj], acc[mi][nj], 0, 0, 0);
            }
        __builtin_amdgcn_sched_barrier(0);
        __builtin_amdgcn_s_barrier();              // all reads done before re-stage
    }

    int colb = kt * 128 + wk * 64 + (l & 15);
    float cn[4];
#pragma unroll
    for (int nj = 0; nj < 4; ++nj) {
        int kc = b * NK + colb + nj * 16;
        cn[nj] = cnP[kc * 3] + cnP[kc * 3 + 1] + cnP[kc * 3 + 2];
    }
    size_t prow = (size_t)b * NM + mOff + mt * 128 + wm * 64 + (l >> 4) * 4;
#pragma unroll
    for (int mi = 0; mi < 4; ++mi) {
#pragma unroll
        for (int rg = 0; rg < 4; ++rg) {
            float bv = 1e30f; int bi = 0;
#pragma unroll
            for (int nj = 0; nj < 4; ++nj) {
                float s = cn[nj] - 2.0f * acc[mi][nj][rg];
                int ki = colb + nj * 16;
                if (s < bv) { bv = s; bi = ki; }
            }
#pragma unroll
            for (int off = 1; off < 16; off <<= 1) {
                float ov = __shfl_xor(bv, off);
                int   oi = __shfl_xor(bi, off);
                if (ov < bv || (ov == bv && oi < bi)) { bv = ov; bi = oi; }
            }
            if ((l & 15) == 0) {
                unsigned u = __float_as_uint(bv);
                unsigned key = (u >> 31) ? ~u : (u | 0x80000000u);
                atomicMin(&packed[prow + mi * 16 + rg],
                          ((unsigned long long)key << 32) | (unsigned)bi);
            }
        }
    }
}

// ---------------- build CSR lists + position->center map + reset other ------
__global__ __launch_bounds__(1024) void k_lists(
    const unsigned long long* __restrict__ packed, int selfSeed,
    unsigned long long* __restrict__ packedOther,
    int2* __restrict__ cb, int* __restrict__ lstIdx, int* __restrict__ ctrOf)
{
    __shared__ int cntL[NK];
    __shared__ int wsum[16];
    __shared__ int cursor[NK];
    __shared__ int aSh[NM];
    int b = blockIdx.x, tid = threadIdx.x;
    cntL[tid] = 0;
    __syncthreads();
    for (int m = tid; m < NM; m += 1024) {
        int a;
        if (selfSeed && m < NK) a = m;   // iter1: data row m IS center m
        else a = (int)(unsigned)(packed[(size_t)b * NM + m] & 0xffffffffull);
        aSh[m] = a;
        atomicAdd(&cntL[a], 1);
        packedOther[(size_t)b * NM + m] = ~0ull;
    }
    __syncthreads();
    int v = cntL[tid];
    int lane = tid & 63, wv = tid >> 6;
    int x = v;                           // wave-level inclusive scan
#pragma unroll
    for (int off = 1; off < 64; off <<= 1) {
        int y = __shfl_up(x, off);
        if (lane >= off) x += y;
    }
    if (lane == 63) wsum[wv] = x;
    __syncthreads();
    if (tid < 16) {                      // scan the 16 wave totals
        int s = wsum[tid];
        int e = s;
#pragma unroll
        for (int off = 1; off < 16; off <<= 1) {
            int y = __shfl_up(e, off, 16);
            if (tid >= off) e += y;
        }
        wsum[tid] = e - s;               // exclusive wave prefix
    }
    __syncthreads();
    int base = x + wsum[wv] - v;         // global exclusive prefix
    cursor[tid] = base;
    cb[b * NK + tid] = make_int2(v, base);
    __syncthreads();
    for (int m = tid; m < NM; m += 1024) {
        int a = aSh[m];
        int pos = atomicAdd(&cursor[a], 1);
        lstIdx[(size_t)b * NM + pos] = m;
        ctrOf[(size_t)b * NM + pos] = a;
    }
}

// ---------------- stage A: per-8-position segment partial sums --------------
__global__ __launch_bounds__(256) void k_part(
    const float* __restrict__ memFS, const float* __restrict__ V, int t,
    const float* __restrict__ cntFS,
    const int* __restrict__ lstIdx, const int* __restrict__ ctrOf,
    float* __restrict__ part, float* __restrict__ partW)
{
    int g = blockIdx.x * 4 + (threadIdx.x >> 6);   // 0..1919
    int l = threadIdx.x & 63;
    int b = g / 480;
    int rem = g - b * 480;
    int seg = rem / 3, c = rem - seg * 3;
    int pos0 = seg * 8;
    const int* li = lstIdx + (size_t)b * NM;
    const int* co = ctrOf + (size_t)b * NM;
    int ctr[8]; float wg[8]; float4 xv[8];
#pragma unroll
    for (int i = 0; i < 8; ++i) {
        int p = pos0 + i;
        ctr[i] = co[p];
        int mm = li[p];
        wg[i] = (mm < NK) ? cntFS[b * NK + mm] : 1.0f;
        const float4* dr = (mm < NK)
            ? (const float4*)(memFS + ((size_t)b * NK + mm) * ND)
            : (const float4*)(V + (((size_t)b * NT + t) * NN + (mm - NK)) * (size_t)ND);
        xv[i] = dr[c * 64 + l];
    }
    float4 acc; float sw; int cur = ctr[0];
    acc.x = wg[0] * xv[0].x; acc.y = wg[0] * xv[0].y;
    acc.z = wg[0] * xv[0].z; acc.w = wg[0] * xv[0].w;
    sw = wg[0];
#pragma unroll
    for (int i = 1; i < 8; ++i) {
        if (ctr[i] != cur) {   // wave-uniform branch
            int e = pos0 + i - 1;
            ((float4*)(part + ((size_t)b * NM + e) * ND))[c * 64 + l] = acc;
            if (c == 0 && l == 0) partW[b * NM + e] = sw;
            cur = ctr[i];
            acc.x = wg[i] * xv[i].x; acc.y = wg[i] * xv[i].y;
            acc.z = wg[i] * xv[i].z; acc.w = wg[i] * xv[i].w;
            sw = wg[i];
        } else {
            acc.x += wg[i] * xv[i].x; acc.y += wg[i] * xv[i].y;
            acc.z += wg[i] * xv[i].z; acc.w += wg[i] * xv[i].w;
            sw += wg[i];
        }
    }
    int e = pos0 + 7;
    ((float4*)(part + ((size_t)b * NM + e) * ND))[c * 64 + l] = acc;
    if (c == 0 && l == 0) partW[b * NM + e] = sw;
}

// ---------------- stage B: combine segment partials, write center ----------
__global__ __launch_bounds__(256) void k_upd(
    const float* __restrict__ Cen,
    const int2* __restrict__ cb,
    const float* __restrict__ part, const float* __restrict__ partW,
    float* __restrict__ Cout, float* __restrict__ cntOut,
    f16* __restrict__ outH, f16* __restrict__ outL, int outStride,
    float* __restrict__ cnP)
{
    int g = blockIdx.x * 4 + (threadIdx.x >> 6);   // 0..12287
    int lane = threadIdx.x & 63;
    int row = g / 3, c = g - row * 3;              // row = b*NK+k, chunk c
    int b = row >> 10, k = row & 1023;
    int2 cnb = cb[row];
    int n = cnb.x, base = cnb.y;
    float4 acc = {0.f, 0.f, 0.f, 0.f};
    float sumw = 0.f;
    if (n > 0) {
        int last = base + n - 1;
        int s1 = last >> 3;
        for (int s = base >> 3; s <= s1; ++s) {    // streamed, independent loads
            int e = (8 * s + 7 < last) ? (8 * s + 7) : last;
            float4 x = ((const float4*)(part + ((size_t)b * NM + e) * ND))[c * 64 + lane];
            acc.x += x.x; acc.y += x.y; acc.z += x.z; acc.w += x.w;
            sumw += partW[b * NM + e];
        }
    }
    float4 vv;
    if (sumw < 1e-6f) {
        vv = ((const float4*)(Cen + (size_t)row * ND))[c * 64 + lane];
        sumw = (n > 0) ? sumw : 0.f;
    } else {
        float inv = 1.0f / (sumw + 1e-8f);
        vv.x = acc.x * inv; vv.y = acc.y * inv; vv.z = acc.z * inv; vv.w = acc.w * inv;
    }
    ((float4*)(Cout + (size_t)row * ND))[c * 64 + lane] = vv;
    f16x4 h, lo;
    h[0] = (f16)vv.x; lo[0] = (f16)(vv.x - (float)h[0]);
    h[1] = (f16)vv.y; lo[1] = (f16)(vv.y - (float)h[1]);
    h[2] = (f16)vv.z; lo[2] = (f16)(vv.z - (float)h[2]);
    h[3] = (f16)vv.w; lo[3] = (f16)(vv.w - (float)h[3]);
    ((f16x4*)(outH + ((size_t)b * outStride + k) * ND))[c * 64 + lane] = h;
    ((f16x4*)(outL + ((size_t)b * outStride + k) * ND))[c * 64 + lane] = lo;
    float s2 = vv.x * vv.x + vv.y * vv.y + vv.z * vv.z + vv.w * vv.w;
#pragma unroll
    for (int off = 32; off; off >>= 1) s2 += __shfl_xor(s2, off);
    if (lane == 0) cnP[row * 3 + c] = s2;
    if (lane == 0 && c == 0) cntOut[row] = sumw;
}

// ---------------- host ----------------
extern "C" void kernel_launch(void* const* d_in, const int* in_sizes, int n_in,
                              void* d_out, int out_size, void* d_ws, size_t ws_size,
                              hipStream_t stream) {
    const float* V = (const float*)d_in[0];
    float* out = (float*)d_out;
    char* p = (char*)d_ws;
    auto take = [&](size_t bytes) { char* r = p; p += (bytes + 255) & ~(size_t)255; return r; };
    const size_t memB = (size_t)NB * NK * ND * 4;
    float* mem0 = (float*)take(memB);
    float* mem1 = (float*)take(memB);
    float* cnt0 = (float*)take(NB * NK * 4);
    float* cnt1 = (float*)take(NB * NK * 4);
    float* cntS = (float*)take(NB * NK * 4);
    float* cnP  = (float*)take(NB * NK * 3 * 4);
    unsigned long long* packed0 = (unsigned long long*)take(NB * NM * 8);
    unsigned long long* packed1 = (unsigned long long*)take(NB * NM * 8);
    int2* cbBuf  = (int2*)take(NB * NK * 8);
    int*  lstIdx = (int*)take(NB * NM * 4);
    int*  ctrOf  = (int*)take(NB * NM * 4);
    float* partW = (float*)take(NB * NM * 4);
    float* partB = (float*)take((size_t)NB * NM * ND * 4);
    f16* dataH = (f16*)take((size_t)NB * NM * ND * 2);
    f16* dataL = (f16*)take((size_t)NB * NM * ND * 2);
    f16* cenH  = (f16*)take((size_t)NB * NK * ND * 2);
    f16* cenL  = (f16*)take((size_t)NB * NK * ND * 2);

    k_init<<<1024, 256, 0, stream>>>(V, mem0, cnt0, dataH, dataL, cnP, packed0);

    float* mem[2] = {mem0, mem1};
    float* cnt[2] = {cnt0, cnt1};

    for (int f = 0; f < NFRAMES; ++f) {
        int s = f & 1, t = NINIT + f;
        float* mFS = mem[s];
        float* cFS = cnt[s];

        k_prep<<<256, 256, 0, stream>>>(V, t, dataH, dataL);

        // iter 1: centers = memory rows; rows 0..1023 provably self-assign ->
        // score only the 256 new tokens (MT=64 split-D: 4 mTiles x 16 kt x 4 b).
        k_score<64><<<256, 512, 0, stream>>>(dataH, dataL, dataH, dataL, NM, 1024, 4, cnP, packed0);
        k_lists<<<NB, 1024, 0, stream>>>(packed0, 1, packed1, cbBuf, lstIdx, ctrOf);
        k_part<<<480, 256, 0, stream>>>(mFS, V, t, cFS, lstIdx, ctrOf, partB, partW);
        k_upd<<<3072, 256, 0, stream>>>(mFS, cbBuf, partB, partW,
                                        out, cntS, cenH, cenL, NK, cnP);

        // iter 2: centers = tmp centers in d_out (split in cenH/L); full score
        // with the R6 4-wave 128x128 dbuf structure (4 b x 10 mt x 8 kt = 320).
        k_score2<<<320, 256, 0, stream>>>(dataH, dataL, cenH, cenL, NK, 0, 10, cnP, packed1);
        k_lists<<<NB, 1024, 0, stream>>>(packed1, 0, packed0, cbBuf, lstIdx, ctrOf);
        k_part<<<480, 256, 0, stream>>>(mFS, V, t, cFS, lstIdx, ctrOf, partB, partW);
        float* dst = (f == NFRAMES - 1) ? out : mem[1 - s];
        k_upd<<<3072, 256, 0, stream>>>(out, cbBuf, partB, partW,
                                        dst, cnt[1 - s], dataH, dataL, NM, cnP);
    }
}